// Round 1
// baseline (11748.344 us; speedup 1.0000x reference)
//
#include <hip/hip_runtime.h>
#include <hip/hip_bf16.h>

// Problem constants (B,S,D,H fixed by the reference)
constexpr int kB  = 4;
constexpr int kS  = 2048;
constexpr int kD  = 1024;
constexpr int kH  = 16;
constexpr int kDH = 64;          // D / H
constexpr int kM  = kB * kS;     // 8192 rows
constexpr int k3D = 3 * kD;      // 3072

// ---------------------------------------------------------------------------
// C[M][N] = A[M][K] @ Bt[N][K]^T + bias[N]
// A row stride = lda (so we can read the Q-slots out of the qkv buffer).
// 64x64 tile, BK=16, 256 threads, 4x4 micro-tile, fp32.
// ---------------------------------------------------------------------------
template <int N, int K>
__global__ __launch_bounds__(256) void gemm_bt_bias(
    const float* __restrict__ A, int lda,
    const float* __restrict__ Bt,
    const float* __restrict__ bias,
    float* __restrict__ C) {
  // +4 pad: keeps each LDS row 16B-aligned (68*4B = 272B = 17*16B) so the
  // 4-consecutive reads below can fold to ds_read_b128; write aliasing is
  // only 2-way (free on gfx950 per bank-conflict measurements).
  __shared__ float As[16][68];
  __shared__ float Bs[16][68];

  const int t  = threadIdx.x;
  const int tx = t & 15;          // 16 thread cols
  const int ty = t >> 4;          // 16 thread rows
  const int row0 = blockIdx.y * 64;
  const int col0 = blockIdx.x * 64;

  // staging assignment: thread loads one float4 of A and of B per k-tile
  const int lr = t >> 2;          // 0..63 tile row
  const int lk = (t & 3) * 4;     // 0,4,8,12 k offset
  const float* aptr = A  + (size_t)(row0 + lr) * lda + lk;
  const float* bptr = Bt + (size_t)(col0 + lr) * K   + lk;

  float acc[4][4] = {};

  for (int k0 = 0; k0 < K; k0 += 16) {
    float4 av = *(const float4*)(aptr + k0);
    float4 bv = *(const float4*)(bptr + k0);
    As[lk + 0][lr] = av.x; As[lk + 1][lr] = av.y;
    As[lk + 2][lr] = av.z; As[lk + 3][lr] = av.w;
    Bs[lk + 0][lr] = bv.x; Bs[lk + 1][lr] = bv.y;
    Bs[lk + 2][lr] = bv.z; Bs[lk + 3][lr] = bv.w;
    __syncthreads();

#pragma unroll
    for (int kk = 0; kk < 16; ++kk) {
      float ra[4], rb[4];
#pragma unroll
      for (int i = 0; i < 4; ++i) ra[i] = As[kk][ty * 4 + i];
#pragma unroll
      for (int j = 0; j < 4; ++j) rb[j] = Bs[kk][tx * 4 + j];
#pragma unroll
      for (int i = 0; i < 4; ++i)
#pragma unroll
        for (int j = 0; j < 4; ++j) acc[i][j] += ra[i] * rb[j];
    }
    __syncthreads();
  }

#pragma unroll
  for (int i = 0; i < 4; ++i) {
    const size_t r = (size_t)(row0 + ty * 4 + i);
    float* crow = C + r * N + col0 + tx * 4;
#pragma unroll
    for (int j = 0; j < 4; ++j) crow[j] = acc[i][j] + bias[col0 + tx * 4 + j];
  }
}

// ---------------------------------------------------------------------------
// Attention: one block (256 thr) per (b, h, query row).
// qkv layout: [B*S][3D]; q at col h*64, k at 1024+h*64, v at 2048+h*64.
// Writes the attention output IN-PLACE over the q slot of its own row —
// race-free: that slot is read only by this block, before the write.
// ---------------------------------------------------------------------------
__global__ __launch_bounds__(256) void attention_kernel(
    float* __restrict__ qkv, const int* __restrict__ cflag) {
  const int x  = blockIdx.x;
  const int qi = x & (kS - 1);
  const int h  = (x >> 11) & (kH - 1);
  const int b  = x >> 15;
  const int t  = threadIdx.x;

  __shared__ __align__(16) float qs[kDH];
  __shared__ float sc[kS];           // 8 KB score row
  __shared__ float redv[4];
  __shared__ float sM, sSum;
  __shared__ float obuf[4][kDH];

  float* base = qkv + (size_t)(b * kS) * k3D + h * kDH;

  if (t < kDH) qs[t] = base[(size_t)qi * k3D + t];
  const bool causal = (*cflag) != 0;
  const int n = causal ? (qi + 1) : kS;
  __syncthreads();

  // --- scores: sc[j] = dot(q, k_j) / 8 for j < n
  const float4* q4 = (const float4*)qs;
  for (int j = t; j < n; j += 256) {
    const float4* k4 = (const float4*)(base + (size_t)j * k3D + kD);
    float dot = 0.f;
#pragma unroll
    for (int d = 0; d < kDH / 4; ++d) {
      float4 kv = k4[d], qv = q4[d];
      dot += qv.x * kv.x + qv.y * kv.y + qv.z * kv.z + qv.w * kv.w;
    }
    sc[j] = dot * 0.125f;
  }
  __syncthreads();

  // --- row max (block reduce: 64-wide shuffle, then across 4 waves)
  float m = -3.0e38f;
  for (int j = t; j < n; j += 256) m = fmaxf(m, sc[j]);
#pragma unroll
  for (int off = 32; off > 0; off >>= 1) m = fmaxf(m, __shfl_down(m, off));
  const int lane = t & 63, wv = t >> 6;
  if (lane == 0) redv[wv] = m;
  __syncthreads();
  if (t == 0) sM = fmaxf(fmaxf(redv[0], redv[1]), fmaxf(redv[2], redv[3]));
  __syncthreads();
  const float M = sM;

  // --- exp + sum
  float ssum = 0.f;
  for (int j = t; j < n; j += 256) {
    float e = __expf(sc[j] - M);
    sc[j] = e;
    ssum += e;
  }
#pragma unroll
  for (int off = 32; off > 0; off >>= 1) ssum += __shfl_down(ssum, off);
  if (lane == 0) redv[wv] = ssum;
  __syncthreads();
  if (t == 0) sSum = redv[0] + redv[1] + redv[2] + redv[3];
  __syncthreads();
  const float inv = 1.0f / sSum;

  // --- O[d] = sum_j p_j * V[j][d]; lane = d (coalesced V reads), 4 j-groups
  const int d = t & 63, g = t >> 6;
  float o = 0.f;
  for (int j = g; j < n; j += 4)
    o += sc[j] * base[(size_t)j * k3D + 2 * kD + d];
  obuf[g][d] = o;
  __syncthreads();
  if (t < kDH) {
    float r = (obuf[0][t] + obuf[1][t] + obuf[2][t] + obuf[3][t]) * inv;
    base[(size_t)qi * k3D + t] = r;  // overwrite own q slot
  }
}

// ---------------------------------------------------------------------------
extern "C" void kernel_launch(void* const* d_in, const int* in_sizes, int n_in,
                              void* d_out, int out_size, void* d_ws,
                              size_t ws_size, hipStream_t stream) {
  const float* x     = (const float*)d_in[0];  // [B,S,D]
  const float* w_in  = (const float*)d_in[1];  // [3D,D]
  const float* b_in  = (const float*)d_in[2];  // [3D]
  const float* w_out = (const float*)d_in[3];  // [D,D]
  const float* b_out = (const float*)d_in[4];  // [D]
  const int*   cfl   = (const int*)d_in[5];    // scalar
  float* out = (float*)d_out;                  // [B,S,D] fp32
  float* qkv = (float*)d_ws;                   // [8192][3072] fp32 = 100.7 MB

  // 1) fused QKV projection: qkv = x @ w_in^T + b_in
  gemm_bt_bias<k3D, kD>
      <<<dim3(k3D / 64, kM / 64), 256, 0, stream>>>(x, kD, w_in, b_in, qkv);

  // 2) causal attention, output overwrites q slots of qkv
  attention_kernel<<<kB * kH * kS, 256, 0, stream>>>(qkv, cfl);

  // 3) output projection: out = attn_out @ w_out^T + b_out (lda = 3072)
  gemm_bt_bias<kD, kD>
      <<<dim3(kD / 64, kM / 64), 256, 0, stream>>>(qkv, k3D, w_out, b_out, out);
}

// Round 2
// 1924.474 us; speedup vs baseline: 6.1047x; 6.1047x over previous
//
#include <hip/hip_runtime.h>
#include <hip/hip_bf16.h>

// Problem constants (B,S,D,H fixed by the reference)
constexpr int kB  = 4;
constexpr int kS  = 2048;
constexpr int kD  = 1024;
constexpr int kH  = 16;
constexpr int kDH = 64;          // D / H
constexpr int kM  = kB * kS;     // 8192 rows
constexpr int k3D = 3 * kD;      // 3072

// ---------------------------------------------------------------------------
// C[M][N] = A[M][K] @ Bt[N][K]^T + bias[N]   (fp32, 64x64 tile, 4x4 micro)
// ---------------------------------------------------------------------------
template <int N, int K>
__global__ __launch_bounds__(256) void gemm_bt_bias(
    const float* __restrict__ A, int lda,
    const float* __restrict__ Bt,
    const float* __restrict__ bias,
    float* __restrict__ C) {
  __shared__ float As[16][68];
  __shared__ float Bs[16][68];

  const int t  = threadIdx.x;
  const int tx = t & 15;
  const int ty = t >> 4;
  const int row0 = blockIdx.y * 64;
  const int col0 = blockIdx.x * 64;

  const int lr = t >> 2;          // 0..63 tile row
  const int lk = (t & 3) * 4;     // 0,4,8,12 k offset
  const float* aptr = A  + (size_t)(row0 + lr) * lda + lk;
  const float* bptr = Bt + (size_t)(col0 + lr) * K   + lk;

  float acc[4][4] = {};

  for (int k0 = 0; k0 < K; k0 += 16) {
    float4 av = *(const float4*)(aptr + k0);
    float4 bv = *(const float4*)(bptr + k0);
    As[lk + 0][lr] = av.x; As[lk + 1][lr] = av.y;
    As[lk + 2][lr] = av.z; As[lk + 3][lr] = av.w;
    Bs[lk + 0][lr] = bv.x; Bs[lk + 1][lr] = bv.y;
    Bs[lk + 2][lr] = bv.z; Bs[lk + 3][lr] = bv.w;
    __syncthreads();

#pragma unroll
    for (int kk = 0; kk < 16; ++kk) {
      float ra[4], rb[4];
#pragma unroll
      for (int i = 0; i < 4; ++i) ra[i] = As[kk][ty * 4 + i];
#pragma unroll
      for (int j = 0; j < 4; ++j) rb[j] = Bs[kk][tx * 4 + j];
#pragma unroll
      for (int i = 0; i < 4; ++i)
#pragma unroll
        for (int j = 0; j < 4; ++j) acc[i][j] += ra[i] * rb[j];
    }
    __syncthreads();
  }

#pragma unroll
  for (int i = 0; i < 4; ++i) {
    const size_t r = (size_t)(row0 + ty * 4 + i);
    float* crow = C + r * N + col0 + tx * 4;
#pragma unroll
    for (int j = 0; j < 4; ++j) crow[j] = acc[i][j] + bias[col0 + tx * 4 + j];
  }
}

// ---------------------------------------------------------------------------
// Flash-style tiled attention, fp32.
// One block (256 thr) per (b, h, 64-query tile). K/V staged in LDS, shared
// across the 64 queries. Online softmax state (m,l) lives in registers,
// replicated across each row's 16-lane group (reduced via __shfl_xor 1..8).
// Output overwrites the Q slots of this block's own rows (race-free: no other
// block reads those slots).
// ---------------------------------------------------------------------------
__global__ __launch_bounds__(256) void flash_attn(
    float* __restrict__ qkv, const int* __restrict__ cflag) {
  // descending qt: long (high-qt) blocks dispatch first -> better tail balance
  const int qt = (int)(gridDim.x - 1 - blockIdx.x);
  const int h  = blockIdx.y;
  const int b  = blockIdx.z;
  const int t  = threadIdx.x;
  const int tx = t & 15;          // d / k column group
  const int ty = t >> 4;          // q row group

  __shared__ float Qs[64][68];    // [d][q]  (transposed)
  __shared__ float Ks[64][68];    // [d][k]  (transposed)
  __shared__ float Vs[64][68];    // [k][d]  (natural)
  __shared__ float Ps[64][68];    // [q][k]  (natural)

  float* base = qkv + (size_t)(b * kS) * k3D + h * kDH;
  const int  q0     = qt * 64;
  const bool causal = (*cflag) != 0;
  const int  ntiles = causal ? (qt + 1) : (kS / 64);

  // ---- stage Q tile (transposed), once
  const int lr = t >> 2;          // 0..63 tile row
  const int lk = (t & 3) * 4;     // 0,4,8,12
#pragma unroll
  for (int p = 0; p < 4; ++p) {
    const int d = p * 16 + lk;
    float4 qv = *(const float4*)(base + (size_t)(q0 + lr) * k3D + d);
    Qs[d + 0][lr] = qv.x; Qs[d + 1][lr] = qv.y;
    Qs[d + 2][lr] = qv.z; Qs[d + 3][lr] = qv.w;
  }

  float m[4], l[4], o[4][4];
#pragma unroll
  for (int i = 0; i < 4; ++i) {
    m[i] = -3.0e38f; l[i] = 0.f;
#pragma unroll
    for (int j = 0; j < 4; ++j) o[i][j] = 0.f;
  }

  for (int kt = 0; kt < ntiles; ++kt) {
    const int k0 = kt * 64;
    __syncthreads();  // prior PV reads of Ks/Vs done; Qs visible on iter 0

    // ---- stage K (transposed) and V (natural)
#pragma unroll
    for (int p = 0; p < 4; ++p) {
      const int d = p * 16 + lk;
      const float* rowp = base + (size_t)(k0 + lr) * k3D;
      float4 kv = *(const float4*)(rowp + kD + d);
      float4 vv = *(const float4*)(rowp + 2 * kD + d);
      Ks[d + 0][lr] = kv.x; Ks[d + 1][lr] = kv.y;
      Ks[d + 2][lr] = kv.z; Ks[d + 3][lr] = kv.w;
      *(float4*)&Vs[lr][d] = vv;
    }
    __syncthreads();

    // ---- S = Q K^T / 8 for this tile (4x4 per thread)
    float s[4][4] = {};
#pragma unroll 16
    for (int kk = 0; kk < 64; ++kk) {
      float4 qa = *(const float4*)&Qs[kk][ty * 4];
      float4 kb = *(const float4*)&Ks[kk][tx * 4];
      s[0][0] += qa.x * kb.x; s[0][1] += qa.x * kb.y; s[0][2] += qa.x * kb.z; s[0][3] += qa.x * kb.w;
      s[1][0] += qa.y * kb.x; s[1][1] += qa.y * kb.y; s[1][2] += qa.y * kb.z; s[1][3] += qa.y * kb.w;
      s[2][0] += qa.z * kb.x; s[2][1] += qa.z * kb.y; s[2][2] += qa.z * kb.z; s[2][3] += qa.z * kb.w;
      s[3][0] += qa.w * kb.x; s[3][1] += qa.w * kb.y; s[3][2] += qa.w * kb.z; s[3][3] += qa.w * kb.w;
    }
#pragma unroll
    for (int i = 0; i < 4; ++i)
#pragma unroll
      for (int j = 0; j < 4; ++j) s[i][j] *= 0.125f;

    if (causal && kt == qt) {
#pragma unroll
      for (int i = 0; i < 4; ++i)
#pragma unroll
        for (int j = 0; j < 4; ++j)
          if (tx * 4 + j > ty * 4 + i) s[i][j] = -3.0e38f;
    }

    // ---- online softmax (per q-row: reduce across the 16-lane tx group)
#pragma unroll
    for (int i = 0; i < 4; ++i) {
      float mx = fmaxf(fmaxf(s[i][0], s[i][1]), fmaxf(s[i][2], s[i][3]));
#pragma unroll
      for (int off = 1; off < 16; off <<= 1) mx = fmaxf(mx, __shfl_xor(mx, off));
      const float mn = fmaxf(m[i], mx);
      const float alpha = __expf(m[i] - mn);
      m[i] = mn;
      float e0 = __expf(s[i][0] - mn), e1 = __expf(s[i][1] - mn);
      float e2 = __expf(s[i][2] - mn), e3 = __expf(s[i][3] - mn);
      float rs = e0 + e1 + e2 + e3;
#pragma unroll
      for (int off = 1; off < 16; off <<= 1) rs += __shfl_xor(rs, off);
      l[i] = l[i] * alpha + rs;
#pragma unroll
      for (int j = 0; j < 4; ++j) o[i][j] *= alpha;
      *(float4*)&Ps[ty * 4 + i][tx * 4] = make_float4(e0, e1, e2, e3);
    }
    __syncthreads();

    // ---- O += P V (4x4 per thread; inner over k in steps of 4)
#pragma unroll
    for (int kk = 0; kk < 64; kk += 4) {
      float4 pa[4];
#pragma unroll
      for (int i = 0; i < 4; ++i) pa[i] = *(const float4*)&Ps[ty * 4 + i][kk];
      const float* paf = (const float*)pa;
#pragma unroll
      for (int c = 0; c < 4; ++c) {
        float4 vb = *(const float4*)&Vs[kk + c][tx * 4];
#pragma unroll
        for (int i = 0; i < 4; ++i) {
          const float p = paf[i * 4 + c];
          o[i][0] += p * vb.x; o[i][1] += p * vb.y;
          o[i][2] += p * vb.z; o[i][3] += p * vb.w;
        }
      }
    }
  }

  // ---- epilogue: O /= l, overwrite own Q slots
#pragma unroll
  for (int i = 0; i < 4; ++i) {
    const float inv = 1.0f / l[i];
    float4 r = make_float4(o[i][0] * inv, o[i][1] * inv,
                           o[i][2] * inv, o[i][3] * inv);
    *(float4*)(base + (size_t)(q0 + ty * 4 + i) * k3D + tx * 4) = r;
  }
}

// ---------------------------------------------------------------------------
extern "C" void kernel_launch(void* const* d_in, const int* in_sizes, int n_in,
                              void* d_out, int out_size, void* d_ws,
                              size_t ws_size, hipStream_t stream) {
  const float* x     = (const float*)d_in[0];  // [B,S,D]
  const float* w_in  = (const float*)d_in[1];  // [3D,D]
  const float* b_in  = (const float*)d_in[2];  // [3D]
  const float* w_out = (const float*)d_in[3];  // [D,D]
  const float* b_out = (const float*)d_in[4];  // [D]
  const int*   cfl   = (const int*)d_in[5];    // scalar
  float* out = (float*)d_out;                  // [B,S,D] fp32
  float* qkv = (float*)d_ws;                   // [8192][3072] fp32 = 100.7 MB

  // 1) fused QKV projection: qkv = x @ w_in^T + b_in
  gemm_bt_bias<k3D, kD>
      <<<dim3(k3D / 64, kM / 64), 256, 0, stream>>>(x, kD, w_in, b_in, qkv);

  // 2) causal flash attention, output overwrites q slots of qkv
  flash_attn<<<dim3(kS / 64, kH, kB), 256, 0, stream>>>(qkv, cfl);

  // 3) output projection: out = attn_out @ w_out^T + b_out (lda = 3072)
  gemm_bt_bias<kD, kD>
      <<<dim3(kD / 64, kM / 64), 256, 0, stream>>>(qkv, k3D, w_out, b_out, out);
}

// Round 3
// 468.689 us; speedup vs baseline: 25.0664x; 4.1061x over previous
//
#include <hip/hip_runtime.h>
#include <stdint.h>

// Problem constants (B,S,D,H fixed by the reference)
constexpr int kB  = 4;
constexpr int kS  = 2048;
constexpr int kD  = 1024;
constexpr int kH  = 16;
constexpr int kDH = 64;
constexpr int kM  = kB * kS;     // 8192
constexpr int k3D = 3 * kD;      // 3072

typedef __attribute__((ext_vector_type(8))) short short8;  // 8 bf16 (4 VGPRs)
typedef __attribute__((ext_vector_type(4))) float f32x4;   // MFMA C/D

__device__ __forceinline__ unsigned short f2bf(float f) {
  unsigned u = __float_as_uint(f);
  u += 0x7fffu + ((u >> 16) & 1u);   // RNE
  return (unsigned short)(u >> 16);
}

// async global->LDS, 16B per lane. LDS dest must be wave-uniform base + lane*16.
__device__ __forceinline__ void async16(const void* g, void* l) {
  __builtin_amdgcn_global_load_lds(
      (const __attribute__((address_space(1))) unsigned int*)g,
      (__attribute__((address_space(3))) unsigned int*)l, 16, 0, 0);
}

// ---------------------------------------------------------------------------
// fp32 -> bf16 elementwise convert (vectorized x4)
// ---------------------------------------------------------------------------
__global__ __launch_bounds__(256) void cvt_bf16(
    const float* __restrict__ in, unsigned short* __restrict__ o, int n4) {
  int i = blockIdx.x * 256 + threadIdx.x;
  if (i >= n4) return;
  float4 v = ((const float4*)in)[i];
  ushort4 r;
  r.x = f2bf(v.x); r.y = f2bf(v.y); r.z = f2bf(v.z); r.w = f2bf(v.w);
  ((ushort4*)o)[i] = r;
}

// ---------------------------------------------------------------------------
// MFMA GEMM: C[M][N] = A[M][K](bf16) @ Bt[N][K](bf16)^T + bias (fp32 acc).
// 128x128 tile, BK=32, 256 thr = 4 waves in 2x2, 16 mfma_16x16x32 per wave/iter.
// LDS chunk-order [kchunk 0..3][row 0..127][8 bf16]: global_load_lds staging is
// lane-contiguous (no pad possible) AND frag ds_read_b128 is 2-way = free.
// ---------------------------------------------------------------------------
template <bool OUT_BF16>
__global__ __launch_bounds__(256) void gemm_mfma(
    const unsigned short* __restrict__ A, int lda,
    const unsigned short* __restrict__ Bt, int ldb,
    const float* __restrict__ bias, void* __restrict__ Cp, int ldc, int K) {
  __shared__ unsigned short As[4096];  // 8 KB
  __shared__ unsigned short Bs[4096];
  const int t = threadIdx.x;
  const int lane = t & 63, l15 = lane & 15, quad = lane >> 4, w = t >> 6;
  const int row0 = blockIdx.y * 128, col0 = blockIdx.x * 128;
  const int wm = (w & 1) * 64, wn = (w >> 1) * 64;

  f32x4 acc[4][4] = {};

  const int q1 = t, q2 = t + 256;  // chunk ids; q = t keeps wave-contiguity
  const unsigned short* a1 = A  + (size_t)(row0 + (q1 & 127)) * lda + (q1 >> 7) * 8;
  const unsigned short* a2 = A  + (size_t)(row0 + (q2 & 127)) * lda + (q2 >> 7) * 8;
  const unsigned short* b1 = Bt + (size_t)(col0 + (q1 & 127)) * ldb + (q1 >> 7) * 8;
  const unsigned short* b2 = Bt + (size_t)(col0 + (q2 & 127)) * ldb + (q2 >> 7) * 8;

  for (int k0 = 0; k0 < K; k0 += 32) {
    async16(a1 + k0, As + q1 * 8);
    async16(a2 + k0, As + q2 * 8);
    async16(b1 + k0, Bs + q1 * 8);
    async16(b2 + k0, Bs + q2 * 8);
    __syncthreads();  // drains vmcnt (compiler emits vmcnt(0) before barrier)

    short8 af[4], bf[4];
#pragma unroll
    for (int mt = 0; mt < 4; ++mt)
      af[mt] = *(const short8*)(As + (quad * 128 + wm + mt * 16 + l15) * 8);
#pragma unroll
    for (int nt = 0; nt < 4; ++nt)
      bf[nt] = *(const short8*)(Bs + (quad * 128 + wn + nt * 16 + l15) * 8);
#pragma unroll
    for (int mt = 0; mt < 4; ++mt)
#pragma unroll
      for (int nt = 0; nt < 4; ++nt)
        acc[mt][nt] = __builtin_amdgcn_mfma_f32_16x16x32_bf16(
            af[mt], bf[nt], acc[mt][nt], 0, 0, 0);
    __syncthreads();  // all reads done before next staging overwrites
  }

  float bv[4];
#pragma unroll
  for (int nt = 0; nt < 4; ++nt) bv[nt] = bias[col0 + wn + nt * 16 + l15];
#pragma unroll
  for (int mt = 0; mt < 4; ++mt)
#pragma unroll
    for (int i = 0; i < 4; ++i) {
      const size_t r = (size_t)(row0 + wm + mt * 16 + quad * 4 + i);
#pragma unroll
      for (int nt = 0; nt < 4; ++nt) {
        float v = acc[mt][nt][i] + bv[nt];
        const size_t cidx = r * (size_t)ldc + col0 + wn + nt * 16 + l15;
        if (OUT_BF16) ((unsigned short*)Cp)[cidx] = f2bf(v);
        else          ((float*)Cp)[cidx] = v;
      }
    }
}

// ---------------------------------------------------------------------------
// V transpose: qkvb V-slots [b*S+s][2048 + h*64 + d] -> vtb [(b*16+h)*64+d][s]
// so PV's B-fragment (k-major over keys) stages with contiguous 16B copies.
// ---------------------------------------------------------------------------
__global__ __launch_bounds__(256) void v_transpose(
    const unsigned short* __restrict__ qkvb, unsigned short* __restrict__ vtb) {
  __shared__ unsigned short L[64][72];  // +8 pad: 16B-aligned rows
  const int kt = blockIdx.x, h = blockIdx.y, b = blockIdx.z;
  const int t = threadIdx.x;
  const unsigned short* src = qkvb + (size_t)(b * kS) * k3D + 2 * kD + h * kDH;
#pragma unroll
  for (int p = 0; p < 2; ++p) {
    const int q = t + p * 256;
    const int r = q >> 3, c = q & 7;
    *(short8*)(&L[r][c * 8]) =
        *(const short8*)(src + (size_t)(kt * 64 + r) * k3D + c * 8);
  }
  __syncthreads();
  unsigned short* dst = vtb + (size_t)((b * kH + h) * kDH) * kS + kt * 64;
  const int key2 = (t & 31) * 2, dg = t >> 5;
#pragma unroll
  for (int i = 0; i < 8; ++i) {
    const int d = dg * 8 + i;
    ushort2 v = make_ushort2(L[key2][d], L[key2 + 1][d]);
    *(ushort2*)(dst + (size_t)d * kS + key2) = v;  // coalesced along keys
  }
}

// ---------------------------------------------------------------------------
// MFMA flash attention. Block = (b, h, 64-query tile), 4 waves x 16 q-rows.
// All LDS buffers chunk-ordered [kchunk 0..7][row 0..63][8 bf16] (8 KB each).
// S = QK^T via mfma_16x16x32_bf16 (A: m=lane&15,k=quad*8+j; C: col=lane&15,
// row=quad*4+reg). Online softmax on C layout; P->LDS (wave-private rows, no
// barrier needed) -> A-frag for PV. O stays in C layout; epilogue /l, bf16,
// overwrites own Q slots.
// ---------------------------------------------------------------------------
__global__ __launch_bounds__(256) void flash_attn_mfma(
    unsigned short* __restrict__ qkvb, const unsigned short* __restrict__ vtb,
    const int* __restrict__ cflag) {
  __shared__ unsigned short Qs[4096];
  __shared__ unsigned short Ks[4096];
  __shared__ unsigned short Vt[4096];
  __shared__ unsigned short Ps[4096];

  const int qt = (int)gridDim.x - 1 - (int)blockIdx.x;  // long blocks first
  const int h = blockIdx.y, b = blockIdx.z;
  const int t = threadIdx.x;
  const int lane = t & 63, l15 = lane & 15, quad = lane >> 4, w = t >> 6;
  const int q0 = qt * 64;
  const bool causal = (*cflag) != 0;
  const int ntiles = causal ? (qt + 1) : (kS / 64);

  unsigned short* qbase = qkvb + (size_t)(b * kS) * k3D + h * kDH;
  const unsigned short* vbase = vtb + (size_t)((b * kH + h) * kDH) * kS;

  // stage Q once (visible after first in-loop barrier)
  {
    const int qa = t, qb = t + 256;
    async16(qbase + (size_t)(q0 + (qa & 63)) * k3D + (qa >> 6) * 8, Qs + qa * 8);
    async16(qbase + (size_t)(q0 + (qb & 63)) * k3D + (qb >> 6) * 8, Qs + qb * 8);
  }

  f32x4 O[4] = {};
  float m_i[4], l_i[4];
#pragma unroll
  for (int i = 0; i < 4; ++i) { m_i[i] = -3.0e38f; l_i[i] = 0.f; }

  for (int kt = 0; kt < ntiles; ++kt) {
    const int kk0 = kt * 64;
    __syncthreads();  // prev-iter PV reads done; LDS free for staging
    {
      const int qa = t, qb = t + 256;
      async16(qbase + kD + (size_t)(kk0 + (qa & 63)) * k3D + (qa >> 6) * 8, Ks + qa * 8);
      async16(qbase + kD + (size_t)(kk0 + (qb & 63)) * k3D + (qb >> 6) * 8, Ks + qb * 8);
      async16(vbase + (size_t)(qa & 63) * kS + kk0 + (qa >> 6) * 8, Vt + qa * 8);
      async16(vbase + (size_t)(qb & 63) * kS + kk0 + (qb >> 6) * 8, Vt + qb * 8);
    }
    __syncthreads();  // staging drained

    // ---- S = Q K^T (per wave: 16 q-rows x 64 keys)
    short8 aq0 = *(const short8*)(Qs + (quad * 64 + w * 16 + l15) * 8);
    short8 aq1 = *(const short8*)(Qs + ((4 + quad) * 64 + w * 16 + l15) * 8);
    f32x4 s[4];
#pragma unroll
    for (int n0 = 0; n0 < 4; ++n0) {
      short8 bk0 = *(const short8*)(Ks + (quad * 64 + n0 * 16 + l15) * 8);
      short8 bk1 = *(const short8*)(Ks + ((4 + quad) * 64 + n0 * 16 + l15) * 8);
      f32x4 z = {};
      z = __builtin_amdgcn_mfma_f32_16x16x32_bf16(aq0, bk0, z, 0, 0, 0);
      z = __builtin_amdgcn_mfma_f32_16x16x32_bf16(aq1, bk1, z, 0, 0, 0);
      s[n0] = z;
    }

    // ---- online softmax (row r = q0 + w*16 + quad*4 + i; cols across 16 lanes)
    const int rowbase = q0 + w * 16 + quad * 4;
#pragma unroll
    for (int i = 0; i < 4; ++i) {
      float sv[4];
#pragma unroll
      for (int n0 = 0; n0 < 4; ++n0) sv[n0] = s[n0][i] * 0.125f;
      if (causal && kt == qt) {
#pragma unroll
        for (int n0 = 0; n0 < 4; ++n0)
          if (kk0 + n0 * 16 + l15 > rowbase + i) sv[n0] = -3.0e38f;
      }
      float mx = fmaxf(fmaxf(sv[0], sv[1]), fmaxf(sv[2], sv[3]));
#pragma unroll
      for (int off = 1; off < 16; off <<= 1) mx = fmaxf(mx, __shfl_xor(mx, off));
      const float mn = fmaxf(m_i[i], mx);
      const float al = __expf(m_i[i] - mn);
      m_i[i] = mn;
      float rs = 0.f;
#pragma unroll
      for (int n0 = 0; n0 < 4; ++n0) {
        const float e = __expf(sv[n0] - mn);
        rs += e;
        const int key = n0 * 16 + l15;
        Ps[((key >> 3) * 64 + w * 16 + quad * 4 + i) * 8 + (key & 7)] = f2bf(e);
      }
#pragma unroll
      for (int off = 1; off < 16; off <<= 1) rs += __shfl_xor(rs, off);
      l_i[i] = l_i[i] * al + rs;
#pragma unroll
      for (int n0 = 0; n0 < 4; ++n0) O[n0][i] *= al;
    }

    // ---- O += P V (Ps rows are wave-private: no barrier needed)
    short8 ap0 = *(const short8*)(Ps + (quad * 64 + w * 16 + l15) * 8);
    short8 ap1 = *(const short8*)(Ps + ((4 + quad) * 64 + w * 16 + l15) * 8);
#pragma unroll
    for (int n0 = 0; n0 < 4; ++n0) {
      short8 bv0 = *(const short8*)(Vt + (quad * 64 + n0 * 16 + l15) * 8);
      short8 bv1 = *(const short8*)(Vt + ((4 + quad) * 64 + n0 * 16 + l15) * 8);
      O[n0] = __builtin_amdgcn_mfma_f32_16x16x32_bf16(ap0, bv0, O[n0], 0, 0, 0);
      O[n0] = __builtin_amdgcn_mfma_f32_16x16x32_bf16(ap1, bv1, O[n0], 0, 0, 0);
    }
  }

  // ---- epilogue: /l, bf16, overwrite own Q slots
#pragma unroll
  for (int i = 0; i < 4; ++i) {
    const float inv = 1.0f / l_i[i];
    unsigned short* dst = qbase + (size_t)(q0 + w * 16 + quad * 4 + i) * k3D;
#pragma unroll
    for (int n0 = 0; n0 < 4; ++n0)
      dst[n0 * 16 + l15] = f2bf(O[n0][i] * inv);
  }
}

// ---------------------------------------------------------------------------
extern "C" void kernel_launch(void* const* d_in, const int* in_sizes, int n_in,
                              void* d_out, int out_size, void* d_ws,
                              size_t ws_size, hipStream_t stream) {
  const float* x     = (const float*)d_in[0];
  const float* w_in  = (const float*)d_in[1];
  const float* b_in  = (const float*)d_in[2];
  const float* w_out = (const float*)d_in[3];
  const float* b_out = (const float*)d_in[4];
  const int*   cfl   = (const int*)d_in[5];
  float* out = (float*)d_out;

  // workspace layout (all 16B-aligned), total 92.3 MB
  char* ws = (char*)d_ws;
  unsigned short* qkvb = (unsigned short*)(ws);              // 8192x3072 bf16 = 48 MB
  unsigned short* xb   = (unsigned short*)(ws + 50331648);   // 8192x1024 bf16 = 16 MB
  unsigned short* wib  = (unsigned short*)(ws + 67108864);   // 3072x1024 bf16 =  6 MB
  unsigned short* wob  = (unsigned short*)(ws + 73400320);   // 1024x1024 bf16 =  2 MB
  unsigned short* vtb  = (unsigned short*)(ws + 75497472);   // [b,h,d,s] bf16 = 16 MB

  cvt_bf16<<<kM * kD / 4 / 256, 256, 0, stream>>>(x, xb, kM * kD / 4);
  cvt_bf16<<<k3D * kD / 4 / 256, 256, 0, stream>>>(w_in, wib, k3D * kD / 4);
  cvt_bf16<<<kD * kD / 4 / 256, 256, 0, stream>>>(w_out, wob, kD * kD / 4);

  // 1) qkv = x @ w_in^T + b_in  (bf16 out)
  gemm_mfma<true><<<dim3(k3D / 128, kM / 128), 256, 0, stream>>>(
      xb, kD, wib, kD, b_in, qkvb, k3D, kD);

  // 2) V transpose for PV staging
  v_transpose<<<dim3(kS / 64, kH, kB), 256, 0, stream>>>(qkvb, vtb);

  // 3) flash attention (bf16 MFMA), O overwrites Q slots
  flash_attn_mfma<<<dim3(kS / 64, kH, kB), 256, 0, stream>>>(qkvb, vtb, cfl);

  // 4) out = attn @ w_out^T + b_out (fp32 out; A rows inside qkvb, lda=3072)
  gemm_mfma<false><<<dim3(kD / 128, kM / 128), 256, 0, stream>>>(
      qkvb, k3D, wob, kD, b_out, out, kD, kD);
}

// Round 5
// 407.512 us; speedup vs baseline: 28.8294x; 1.1501x over previous
//
#include <hip/hip_runtime.h>
#include <hip/hip_bf16.h>
#include <stdint.h>

// Problem constants (B,S,D,H fixed by the reference)
constexpr int kB  = 4;
constexpr int kS  = 2048;
constexpr int kD  = 1024;
constexpr int kH  = 16;
constexpr int kDH = 64;
constexpr int kM  = kB * kS;     // 8192
constexpr int k3D = 3 * kD;      // 3072

typedef __attribute__((ext_vector_type(8))) short short8;  // 8 bf16 (4 VGPRs)
typedef __attribute__((ext_vector_type(4))) float f32x4;   // MFMA C/D

__device__ __forceinline__ unsigned short f2bf(float f) {
  unsigned u = __float_as_uint(f);
  u += 0x7fffu + ((u >> 16) & 1u);   // RNE
  return (unsigned short)(u >> 16);
}
__device__ __forceinline__ unsigned pack2bf(float a, float b) {
  return (unsigned)f2bf(a) | ((unsigned)f2bf(b) << 16);
}

// async global->LDS, 16B per lane. LDS dest must be wave-uniform base + lane*16.
__device__ __forceinline__ void async16(const void* g, void* l) {
  __builtin_amdgcn_global_load_lds(
      (const __attribute__((address_space(1))) unsigned int*)g,
      (__attribute__((address_space(3))) unsigned int*)l, 16, 0, 0);
}

// ---------------------------------------------------------------------------
// fp32 -> bf16 elementwise convert (vectorized x4)
// ---------------------------------------------------------------------------
__global__ __launch_bounds__(256) void cvt_bf16(
    const float* __restrict__ in, unsigned short* __restrict__ o, int n4) {
  int i = blockIdx.x * 256 + threadIdx.x;
  if (i >= n4) return;
  float4 v = ((const float4*)in)[i];
  ushort4 r;
  r.x = f2bf(v.x); r.y = f2bf(v.y); r.z = f2bf(v.z); r.w = f2bf(v.w);
  ((ushort4*)o)[i] = r;
}

// ---------------------------------------------------------------------------
// MFMA GEMM: C[M][N] = A[M][K](bf16) @ Bt[N][K](bf16)^T + bias (fp32 acc).
// 128x128 tile, BK=32, 256 thr = 4 waves in 2x2, 16 mfma_16x16x32 per wave/iter.
// QSCALE: multiply (acc+bias) by 0.125 for output cols < kD (the Q columns) —
// folds the attention 1/sqrt(DH) into the projection. Block-uniform since the
// col-1024 boundary is 128-tile aligned.
// ---------------------------------------------------------------------------
template <bool OUT_BF16, bool QSCALE>
__global__ __launch_bounds__(256) void gemm_mfma(
    const unsigned short* __restrict__ A, int lda,
    const unsigned short* __restrict__ Bt, int ldb,
    const float* __restrict__ bias, void* __restrict__ Cp, int ldc, int K) {
  __shared__ unsigned short As[4096];  // 8 KB
  __shared__ unsigned short Bs[4096];
  const int t = threadIdx.x;
  const int lane = t & 63, l15 = lane & 15, quad = lane >> 4, w = t >> 6;
  const int row0 = blockIdx.y * 128, col0 = blockIdx.x * 128;
  const int wm = (w & 1) * 64, wn = (w >> 1) * 64;

  f32x4 acc[4][4] = {};

  const int q1 = t, q2 = t + 256;  // chunk ids; q = t keeps wave-contiguity
  const unsigned short* a1 = A  + (size_t)(row0 + (q1 & 127)) * lda + (q1 >> 7) * 8;
  const unsigned short* a2 = A  + (size_t)(row0 + (q2 & 127)) * lda + (q2 >> 7) * 8;
  const unsigned short* b1 = Bt + (size_t)(col0 + (q1 & 127)) * ldb + (q1 >> 7) * 8;
  const unsigned short* b2 = Bt + (size_t)(col0 + (q2 & 127)) * ldb + (q2 >> 7) * 8;

  for (int k0 = 0; k0 < K; k0 += 32) {
    async16(a1 + k0, As + q1 * 8);
    async16(a2 + k0, As + q2 * 8);
    async16(b1 + k0, Bs + q1 * 8);
    async16(b2 + k0, Bs + q2 * 8);
    __syncthreads();

    short8 af[4], bf[4];
#pragma unroll
    for (int mt = 0; mt < 4; ++mt)
      af[mt] = *(const short8*)(As + (quad * 128 + wm + mt * 16 + l15) * 8);
#pragma unroll
    for (int nt = 0; nt < 4; ++nt)
      bf[nt] = *(const short8*)(Bs + (quad * 128 + wn + nt * 16 + l15) * 8);
#pragma unroll
    for (int mt = 0; mt < 4; ++mt)
#pragma unroll
      for (int nt = 0; nt < 4; ++nt)
        acc[mt][nt] = __builtin_amdgcn_mfma_f32_16x16x32_bf16(
            af[mt], bf[nt], acc[mt][nt], 0, 0, 0);
    __syncthreads();
  }

  const float sc = (QSCALE && col0 < kD) ? 0.125f : 1.0f;
  float bv[4];
#pragma unroll
  for (int nt = 0; nt < 4; ++nt) bv[nt] = bias[col0 + wn + nt * 16 + l15];
#pragma unroll
  for (int mt = 0; mt < 4; ++mt)
#pragma unroll
    for (int i = 0; i < 4; ++i) {
      const size_t r = (size_t)(row0 + wm + mt * 16 + quad * 4 + i);
#pragma unroll
      for (int nt = 0; nt < 4; ++nt) {
        float v = (acc[mt][nt][i] + bv[nt]) * sc;
        const size_t cidx = r * (size_t)ldc + col0 + wn + nt * 16 + l15;
        if (OUT_BF16) ((unsigned short*)Cp)[cidx] = f2bf(v);
        else          ((float*)Cp)[cidx] = v;
      }
    }
}

// ---------------------------------------------------------------------------
// V transpose: qkvb V-slots [b*S+s][2048 + h*64 + d] -> vtb [(b*16+h)*64+d][s]
// ---------------------------------------------------------------------------
__global__ __launch_bounds__(256) void v_transpose(
    const unsigned short* __restrict__ qkvb, unsigned short* __restrict__ vtb) {
  __shared__ unsigned short L[64][72];  // +8 pad: 16B-aligned rows
  const int kt = blockIdx.x, h = blockIdx.y, b = blockIdx.z;
  const int t = threadIdx.x;
  const unsigned short* src = qkvb + (size_t)(b * kS) * k3D + 2 * kD + h * kDH;
#pragma unroll
  for (int p = 0; p < 2; ++p) {
    const int q = t + p * 256;
    const int r = q >> 3, c = q & 7;
    *(short8*)(&L[r][c * 8]) =
        *(const short8*)(src + (size_t)(kt * 64 + r) * k3D + c * 8);
  }
  __syncthreads();
  unsigned short* dst = vtb + (size_t)((b * kH + h) * kDH) * kS + kt * 64;
  const int key2 = (t & 31) * 2, dg = t >> 5;
#pragma unroll
  for (int i = 0; i < 8; ++i) {
    const int d = dg * 8 + i;
    ushort2 v = make_ushort2(L[key2][d], L[key2 + 1][d]);
    *(ushort2*)(dst + (size_t)d * kS + key2) = v;  // coalesced along keys
  }
}

// ---------------------------------------------------------------------------
// MFMA flash attention, S^T formulation.
// Block = (b, h, 128-query tile), 4 waves x 32 q-rows. LDS chunk-ordered
// [kchunk][row][8 bf16] everywhere. S^T = K·Q^T so the C-layout puts q on
// lane&15: row-reduce = 15 in-lane ops + 2 __shfl_xor (quads); each lane holds
// 4 CONSECUTIVE keys per q-row -> packed ds_write_b64 P-stores directly in
// PV's A-fragment layout (wave-private rows: no barrier). Score scale is
// pre-folded into Q by GEMM1.
// ---------------------------------------------------------------------------
__global__ __launch_bounds__(256, 3) void flash_attn_mfma(
    unsigned short* __restrict__ qkvb, const unsigned short* __restrict__ vtb,
    const int* __restrict__ cflag) {
  __shared__ unsigned short Qs[8192];  // [dchunk 0..7][q 0..127][8]   16 KB
  __shared__ unsigned short Ks[4096];  // [dchunk 0..7][key 0..63][8]   8 KB
  __shared__ unsigned short Vt[4096];  // [keychunk 0..7][d 0..63][8]   8 KB
  __shared__ unsigned short Ps[8192];  // [keychunk 0..7][q 0..127][8] 16 KB

  const int qt = (int)gridDim.x - 1 - (int)blockIdx.x;  // long blocks first
  const int h = blockIdx.y, b = blockIdx.z;
  const int t = threadIdx.x;
  const int lane = t & 63, l15 = lane & 15, quad = lane >> 4, w = t >> 6;
  const int q0 = qt * 128;
  const bool causal = (*cflag) != 0;
  const int ntiles = causal ? (2 * qt + 2) : (kS / 64);

  unsigned short* qbase = qkvb + (size_t)(b * kS) * k3D + h * kDH;
  const unsigned short* vbase = vtb + (size_t)((b * kH + h) * kDH) * kS;

  // stage Q once: 1024 chunks, 4 per thread
#pragma unroll
  for (int p = 0; p < 4; ++p) {
    const int c = t + p * 256;
    async16(qbase + (size_t)(q0 + (c & 127)) * k3D + (c >> 7) * 8, Qs + c * 8);
  }

  f32x4 O[2][4] = {};                      // [q-half mt2][d-tile ntd]
  float m_i[2] = {-3.0e38f, -3.0e38f};     // per q-group (q = w*32+nt*16+l15)
  float l_i[2] = {0.f, 0.f};

  for (int kt = 0; kt < ntiles; ++kt) {
    const int kk0 = kt * 64;
    __syncthreads();  // prev-tile K/V/Q reads done
#pragma unroll
    for (int p = 0; p < 2; ++p) {
      const int c = t + p * 256;
      async16(qbase + kD + (size_t)(kk0 + (c & 63)) * k3D + (c >> 6) * 8,
              Ks + c * 8);
      async16(vbase + (size_t)(c & 63) * kS + kk0 + (c >> 6) * 8, Vt + c * 8);
    }
    __syncthreads();  // staging drained

    // ---- S^T = K·Q^T: s[mt][nt]; key = kk0+mt*16+quad*4+reg, q = w*32+nt*16+l15
    short8 bq[2][2];
#pragma unroll
    for (int nt = 0; nt < 2; ++nt)
#pragma unroll
      for (int kf = 0; kf < 2; ++kf)
        bq[nt][kf] = *(const short8*)(
            Qs + ((kf * 4 + quad) * 128 + w * 32 + nt * 16 + l15) * 8);

    f32x4 s[4][2];
#pragma unroll
    for (int mt = 0; mt < 4; ++mt) {
      short8 a0 = *(const short8*)(Ks + ((quad)*64 + mt * 16 + l15) * 8);
      short8 a1 = *(const short8*)(Ks + ((4 + quad) * 64 + mt * 16 + l15) * 8);
#pragma unroll
      for (int nt = 0; nt < 2; ++nt) {
        f32x4 z = {};
        z = __builtin_amdgcn_mfma_f32_16x16x32_bf16(a0, bq[nt][0], z, 0, 0, 0);
        z = __builtin_amdgcn_mfma_f32_16x16x32_bf16(a1, bq[nt][1], z, 0, 0, 0);
        s[mt][nt] = z;
      }
    }

    // ---- online softmax per q-group nt
    float alpha[2];
#pragma unroll
    for (int nt = 0; nt < 2; ++nt) {
      const int gq = q0 + w * 32 + nt * 16 + l15;
      if (causal && kt >= ntiles - 2) {
#pragma unroll
        for (int mt = 0; mt < 4; ++mt)
#pragma unroll
          for (int i = 0; i < 4; ++i)
            if (kk0 + mt * 16 + quad * 4 + i > gq) s[mt][nt][i] = -3.0e38f;
      }
      float mx = -3.0e38f;
#pragma unroll
      for (int mt = 0; mt < 4; ++mt)
#pragma unroll
        for (int i = 0; i < 4; ++i) mx = fmaxf(mx, s[mt][nt][i]);
      mx = fmaxf(mx, __shfl_xor(mx, 16));
      mx = fmaxf(mx, __shfl_xor(mx, 32));
      const float mn = fmaxf(m_i[nt], mx);
      alpha[nt] = __expf(m_i[nt] - mn);
      m_i[nt] = mn;

      float p[4][4];
      float rs = 0.f;
#pragma unroll
      for (int mt = 0; mt < 4; ++mt)
#pragma unroll
        for (int i = 0; i < 4; ++i) {
          p[mt][i] = __expf(s[mt][nt][i] - mn);
          rs += p[mt][i];
        }
      rs += __shfl_xor(rs, 16);
      rs += __shfl_xor(rs, 32);
      l_i[nt] = l_i[nt] * alpha[nt] + rs;

      // packed P store: 4 consecutive keys (mt*16+quad*4 .. +3) at row gq
#pragma unroll
      for (int mt = 0; mt < 4; ++mt) {
        uint2 pk = make_uint2(pack2bf(p[mt][0], p[mt][1]),
                              pack2bf(p[mt][2], p[mt][3]));
        *(uint2*)(Ps + ((mt * 2 + (quad >> 1)) * 128 + w * 32 + nt * 16 + l15) * 8 +
                  (quad & 1) * 4) = pk;
      }
    }

    // ---- rescale O by alpha of its own q-row (row = mt2*16 + quad*4 + i)
#pragma unroll
    for (int mt2 = 0; mt2 < 2; ++mt2)
#pragma unroll
      for (int i = 0; i < 4; ++i) {
        const float a = __shfl(alpha[mt2], quad * 4 + i);
#pragma unroll
        for (int ntd = 0; ntd < 4; ++ntd) O[mt2][ntd][i] *= a;
      }

    // ---- O += P·V (Ps rows wave-private; compiler inserts lgkmcnt)
#pragma unroll
    for (int kf = 0; kf < 2; ++kf) {
      short8 bV[4];
#pragma unroll
      for (int ntd = 0; ntd < 4; ++ntd)
        bV[ntd] = *(const short8*)(Vt + ((kf * 4 + quad) * 64 + ntd * 16 + l15) * 8);
#pragma unroll
      for (int mt2 = 0; mt2 < 2; ++mt2) {
        short8 aP = *(const short8*)(
            Ps + ((kf * 4 + quad) * 128 + w * 32 + mt2 * 16 + l15) * 8);
#pragma unroll
        for (int ntd = 0; ntd < 4; ++ntd)
          O[mt2][ntd] = __builtin_amdgcn_mfma_f32_16x16x32_bf16(
              aP, bV[ntd], O[mt2][ntd], 0, 0, 0);
      }
    }
  }

  // ---- epilogue: /l, bf16, overwrite own Q slots
#pragma unroll
  for (int mt2 = 0; mt2 < 2; ++mt2)
#pragma unroll
    for (int i = 0; i < 4; ++i) {
      const float linv = 1.0f / __shfl(l_i[mt2], quad * 4 + i);
      unsigned short* dst =
          qbase + (size_t)(q0 + w * 32 + mt2 * 16 + quad * 4 + i) * k3D;
#pragma unroll
      for (int ntd = 0; ntd < 4; ++ntd)
        dst[ntd * 16 + l15] = f2bf(O[mt2][ntd][i] * linv);
    }
}

// ---------------------------------------------------------------------------
extern "C" void kernel_launch(void* const* d_in, const int* in_sizes, int n_in,
                              void* d_out, int out_size, void* d_ws,
                              size_t ws_size, hipStream_t stream) {
  const float* x     = (const float*)d_in[0];
  const float* w_in  = (const float*)d_in[1];
  const float* b_in  = (const float*)d_in[2];
  const float* w_out = (const float*)d_in[3];
  const float* b_out = (const float*)d_in[4];
  const int*   cfl   = (const int*)d_in[5];
  float* out = (float*)d_out;

  // workspace layout (all 16B-aligned), total 92.3 MB
  char* ws = (char*)d_ws;
  unsigned short* qkvb = (unsigned short*)(ws);              // 8192x3072 bf16 = 48 MB
  unsigned short* xb   = (unsigned short*)(ws + 50331648);   // 8192x1024 bf16 = 16 MB
  unsigned short* wib  = (unsigned short*)(ws + 67108864);   // 3072x1024 bf16 =  6 MB
  unsigned short* wob  = (unsigned short*)(ws + 73400320);   // 1024x1024 bf16 =  2 MB
  unsigned short* vtb  = (unsigned short*)(ws + 75497472);   // [b,h,d,s] bf16 = 16 MB

  cvt_bf16<<<kM * kD / 4 / 256, 256, 0, stream>>>(x, xb, kM * kD / 4);
  cvt_bf16<<<k3D * kD / 4 / 256, 256, 0, stream>>>(w_in, wib, k3D * kD / 4);
  cvt_bf16<<<kD * kD / 4 / 256, 256, 0, stream>>>(w_out, wob, kD * kD / 4);

  // 1) qkv = x @ w_in^T + b_in (bf16 out; Q cols pre-scaled by 1/8)
  gemm_mfma<true, true><<<dim3(k3D / 128, kM / 128), 256, 0, stream>>>(
      xb, kD, wib, kD, b_in, qkvb, k3D, kD);

  // 2) V transpose for PV staging
  v_transpose<<<dim3(kS / 64, kH, kB), 256, 0, stream>>>(qkvb, vtb);

  // 3) flash attention (bf16 MFMA, S^T layout), O overwrites Q slots
  flash_attn_mfma<<<dim3(kS / 128, kH, kB), 256, 0, stream>>>(qkvb, vtb, cfl);

  // 4) out = attn @ w_out^T + b_out (fp32 out; A rows inside qkvb, lda=3072)
  gemm_mfma<false, false><<<dim3(kD / 128, kM / 128), 256, 0, stream>>>(
      qkvb, k3D, wob, kD, b_out, out, kD, kD);
}

// Round 6
// 384.901 us; speedup vs baseline: 30.5230x; 1.0587x over previous
//
#include <hip/hip_runtime.h>
#include <hip/hip_bf16.h>
#include <stdint.h>

// Problem constants (B,S,D,H fixed by the reference)
constexpr int kB  = 4;
constexpr int kS  = 2048;
constexpr int kD  = 1024;
constexpr int kH  = 16;
constexpr int kDH = 64;
constexpr int kM  = kB * kS;     // 8192
constexpr int k3D = 3 * kD;      // 3072

typedef __attribute__((ext_vector_type(8))) short short8;  // 8 bf16 (4 VGPRs)
typedef __attribute__((ext_vector_type(4))) float f32x4;   // MFMA C/D

__device__ __forceinline__ unsigned short f2bf(float f) {
  unsigned u = __float_as_uint(f);
  u += 0x7fffu + ((u >> 16) & 1u);   // RNE
  return (unsigned short)(u >> 16);
}
__device__ __forceinline__ unsigned pack2bf(float a, float b) {
  return (unsigned)f2bf(a) | ((unsigned)f2bf(b) << 16);
}

// async global->LDS, 16B per lane. LDS dest must be wave-uniform base + lane*16.
__device__ __forceinline__ void async16(const void* g, void* l) {
  __builtin_amdgcn_global_load_lds(
      (const __attribute__((address_space(1))) unsigned int*)g,
      (__attribute__((address_space(3))) unsigned int*)l, 16, 0, 0);
}

// ---------------------------------------------------------------------------
// fp32 -> bf16 elementwise convert (vectorized x4)
// ---------------------------------------------------------------------------
__global__ __launch_bounds__(256) void cvt_bf16(
    const float* __restrict__ in, unsigned short* __restrict__ o, int n4) {
  int i = blockIdx.x * 256 + threadIdx.x;
  if (i >= n4) return;
  float4 v = ((const float4*)in)[i];
  ushort4 r;
  r.x = f2bf(v.x); r.y = f2bf(v.y); r.z = f2bf(v.z); r.w = f2bf(v.w);
  ((ushort4*)o)[i] = r;
}

// ---------------------------------------------------------------------------
// MFMA GEMM: C[M][N] = A[M][K](bf16) @ Bt[N][K](bf16)^T + bias (fp32 acc).
// 128x128 tile, BK=32, 256 thr = 4 waves in 2x2, 16 mfma_16x16x32 per wave/iter.
// QSCALE: multiply (acc+bias) by 0.125 for output cols < kD (the Q columns).
// ---------------------------------------------------------------------------
template <bool OUT_BF16, bool QSCALE>
__global__ __launch_bounds__(256) void gemm_mfma(
    const unsigned short* __restrict__ A, int lda,
    const unsigned short* __restrict__ Bt, int ldb,
    const float* __restrict__ bias, void* __restrict__ Cp, int ldc, int K) {
  __shared__ unsigned short As[4096];  // 8 KB
  __shared__ unsigned short Bs[4096];
  const int t = threadIdx.x;
  const int lane = t & 63, l15 = lane & 15, quad = lane >> 4, w = t >> 6;
  const int row0 = blockIdx.y * 128, col0 = blockIdx.x * 128;
  const int wm = (w & 1) * 64, wn = (w >> 1) * 64;

  f32x4 acc[4][4] = {};

  const int q1 = t, q2 = t + 256;  // chunk ids; q = t keeps wave-contiguity
  const unsigned short* a1 = A  + (size_t)(row0 + (q1 & 127)) * lda + (q1 >> 7) * 8;
  const unsigned short* a2 = A  + (size_t)(row0 + (q2 & 127)) * lda + (q2 >> 7) * 8;
  const unsigned short* b1 = Bt + (size_t)(col0 + (q1 & 127)) * ldb + (q1 >> 7) * 8;
  const unsigned short* b2 = Bt + (size_t)(col0 + (q2 & 127)) * ldb + (q2 >> 7) * 8;

  for (int k0 = 0; k0 < K; k0 += 32) {
    async16(a1 + k0, As + q1 * 8);
    async16(a2 + k0, As + q2 * 8);
    async16(b1 + k0, Bs + q1 * 8);
    async16(b2 + k0, Bs + q2 * 8);
    __syncthreads();

    short8 af[4], bf[4];
#pragma unroll
    for (int mt = 0; mt < 4; ++mt)
      af[mt] = *(const short8*)(As + (quad * 128 + wm + mt * 16 + l15) * 8);
#pragma unroll
    for (int nt = 0; nt < 4; ++nt)
      bf[nt] = *(const short8*)(Bs + (quad * 128 + wn + nt * 16 + l15) * 8);
#pragma unroll
    for (int mt = 0; mt < 4; ++mt)
#pragma unroll
      for (int nt = 0; nt < 4; ++nt)
        acc[mt][nt] = __builtin_amdgcn_mfma_f32_16x16x32_bf16(
            af[mt], bf[nt], acc[mt][nt], 0, 0, 0);
    __syncthreads();
  }

  const float sc = (QSCALE && col0 < kD) ? 0.125f : 1.0f;
  float bv[4];
#pragma unroll
  for (int nt = 0; nt < 4; ++nt) bv[nt] = bias[col0 + wn + nt * 16 + l15];
#pragma unroll
  for (int mt = 0; mt < 4; ++mt)
#pragma unroll
    for (int i = 0; i < 4; ++i) {
      const size_t r = (size_t)(row0 + wm + mt * 16 + quad * 4 + i);
#pragma unroll
      for (int nt = 0; nt < 4; ++nt) {
        float v = (acc[mt][nt][i] + bv[nt]) * sc;
        const size_t cidx = r * (size_t)ldc + col0 + wn + nt * 16 + l15;
        if (OUT_BF16) ((unsigned short*)Cp)[cidx] = f2bf(v);
        else          ((float*)Cp)[cidx] = v;
      }
    }
}

// ---------------------------------------------------------------------------
// V transpose: qkvb V-slots [b*S+s][2048 + h*64 + d] -> vtb [(b*16+h)*64+d][s]
// ---------------------------------------------------------------------------
__global__ __launch_bounds__(256) void v_transpose(
    const unsigned short* __restrict__ qkvb, unsigned short* __restrict__ vtb) {
  __shared__ unsigned short L[64][72];  // +8 pad: 16B-aligned rows
  const int kt = blockIdx.x, h = blockIdx.y, b = blockIdx.z;
  const int t = threadIdx.x;
  const unsigned short* src = qkvb + (size_t)(b * kS) * k3D + 2 * kD + h * kDH;
#pragma unroll
  for (int p = 0; p < 2; ++p) {
    const int q = t + p * 256;
    const int r = q >> 3, c = q & 7;
    *(short8*)(&L[r][c * 8]) =
        *(const short8*)(src + (size_t)(kt * 64 + r) * k3D + c * 8);
  }
  __syncthreads();
  unsigned short* dst = vtb + (size_t)((b * kH + h) * kDH) * kS + kt * 64;
  const int key2 = (t & 31) * 2, dg = t >> 5;
#pragma unroll
  for (int i = 0; i < 8; ++i) {
    const int d = dg * 8 + i;
    ushort2 v = make_ushort2(L[key2][d], L[key2 + 1][d]);
    *(ushort2*)(dst + (size_t)d * kS + key2) = v;  // coalesced along keys
  }
}

// ---------------------------------------------------------------------------
// MFMA flash attention, S^T formulation, register-resident Q.
// Block = (b, h, 128-query tile), 4 waves x 32 q-rows.
// Q fragments (bq) are loop-invariant -> hoisted to registers after one
// pre-loop barrier; the 16 KB Q buffer is then reused as the P buffer (QP).
// Aliasing is race-free: each wave reads only its own bq rows (w*32..w*32+31)
// and writes only those same P rows; barrier semantics order all bq reads
// before anyone's first P write. LDS = 32 KB -> 4-5 blocks/CU (was 3).
// ---------------------------------------------------------------------------
__global__ __launch_bounds__(256, 4) void flash_attn_mfma(
    unsigned short* __restrict__ qkvb, const unsigned short* __restrict__ vtb,
    const int* __restrict__ cflag) {
  __shared__ unsigned short QP[8192];  // Q then P: [chunk 0..7][q 0..127][8] 16 KB
  __shared__ unsigned short Ks[4096];  // [dchunk 0..7][key 0..63][8]          8 KB
  __shared__ unsigned short Vt[4096];  // [keychunk 0..7][d 0..63][8]          8 KB

  const int qt = (int)gridDim.x - 1 - (int)blockIdx.x;  // long blocks first
  const int h = blockIdx.y, b = blockIdx.z;
  const int t = threadIdx.x;
  const int lane = t & 63, l15 = lane & 15, quad = lane >> 4, w = t >> 6;
  const int q0 = qt * 128;
  const bool causal = (*cflag) != 0;
  const int ntiles = causal ? (2 * qt + 2) : (kS / 64);

  unsigned short* qbase = qkvb + (size_t)(b * kS) * k3D + h * kDH;
  const unsigned short* vbase = vtb + (size_t)((b * kH + h) * kDH) * kS;

  // stage Q once: 1024 chunks, 4 per thread
#pragma unroll
  for (int p = 0; p < 4; ++p) {
    const int c = t + p * 256;
    async16(qbase + (size_t)(q0 + (c & 127)) * k3D + (c >> 7) * 8, QP + c * 8);
  }
  __syncthreads();  // Q staging drained (all rows, all waves)

  // hoist Q fragments to registers — QP becomes the P buffer afterwards
  short8 bq[2][2];
#pragma unroll
  for (int nt = 0; nt < 2; ++nt)
#pragma unroll
    for (int kf = 0; kf < 2; ++kf)
      bq[nt][kf] = *(const short8*)(
          QP + ((kf * 4 + quad) * 128 + w * 32 + nt * 16 + l15) * 8);

  f32x4 O[2][4] = {};                      // [q-half mt2][d-tile ntd]
  float m_i[2] = {-3.0e38f, -3.0e38f};     // per q-group (q = w*32+nt*16+l15)
  float l_i[2] = {0.f, 0.f};

  for (int kt = 0; kt < ntiles; ++kt) {
    const int kk0 = kt * 64;
    __syncthreads();  // prev-tile K/V/P reads done; all bq reads done (kt=0)
#pragma unroll
    for (int p = 0; p < 2; ++p) {
      const int c = t + p * 256;
      async16(qbase + kD + (size_t)(kk0 + (c & 63)) * k3D + (c >> 6) * 8,
              Ks + c * 8);
      async16(vbase + (size_t)(c & 63) * kS + kk0 + (c >> 6) * 8, Vt + c * 8);
    }
    __syncthreads();  // staging drained

    // ---- S^T = K·Q^T: s[mt][nt]; key = kk0+mt*16+quad*4+reg, q = w*32+nt*16+l15
    f32x4 s[4][2];
#pragma unroll
    for (int mt = 0; mt < 4; ++mt) {
      short8 a0 = *(const short8*)(Ks + ((quad)*64 + mt * 16 + l15) * 8);
      short8 a1 = *(const short8*)(Ks + ((4 + quad) * 64 + mt * 16 + l15) * 8);
#pragma unroll
      for (int nt = 0; nt < 2; ++nt) {
        f32x4 z = {};
        z = __builtin_amdgcn_mfma_f32_16x16x32_bf16(a0, bq[nt][0], z, 0, 0, 0);
        z = __builtin_amdgcn_mfma_f32_16x16x32_bf16(a1, bq[nt][1], z, 0, 0, 0);
        s[mt][nt] = z;
      }
    }

    // ---- online softmax per q-group nt
    float alpha[2];
#pragma unroll
    for (int nt = 0; nt < 2; ++nt) {
      const int gq = q0 + w * 32 + nt * 16 + l15;
      if (causal && kt >= ntiles - 2) {
#pragma unroll
        for (int mt = 0; mt < 4; ++mt)
#pragma unroll
          for (int i = 0; i < 4; ++i)
            if (kk0 + mt * 16 + quad * 4 + i > gq) s[mt][nt][i] = -3.0e38f;
      }
      float mx = -3.0e38f;
#pragma unroll
      for (int mt = 0; mt < 4; ++mt)
#pragma unroll
        for (int i = 0; i < 4; ++i) mx = fmaxf(mx, s[mt][nt][i]);
      mx = fmaxf(mx, __shfl_xor(mx, 16));
      mx = fmaxf(mx, __shfl_xor(mx, 32));
      const float mn = fmaxf(m_i[nt], mx);
      alpha[nt] = __expf(m_i[nt] - mn);
      m_i[nt] = mn;

      float p[4][4];
      float rs = 0.f;
#pragma unroll
      for (int mt = 0; mt < 4; ++mt)
#pragma unroll
        for (int i = 0; i < 4; ++i) {
          p[mt][i] = __expf(s[mt][nt][i] - mn);
          rs += p[mt][i];
        }
      rs += __shfl_xor(rs, 16);
      rs += __shfl_xor(rs, 32);
      l_i[nt] = l_i[nt] * alpha[nt] + rs;

      // packed P store: 4 consecutive keys (mt*16+quad*4 .. +3) at row gq
#pragma unroll
      for (int mt = 0; mt < 4; ++mt) {
        uint2 pk = make_uint2(pack2bf(p[mt][0], p[mt][1]),
                              pack2bf(p[mt][2], p[mt][3]));
        *(uint2*)(QP + ((mt * 2 + (quad >> 1)) * 128 + w * 32 + nt * 16 + l15) * 8 +
                  (quad & 1) * 4) = pk;
      }
    }

    // ---- rescale O by alpha of its own q-row (row = mt2*16 + quad*4 + i)
#pragma unroll
    for (int mt2 = 0; mt2 < 2; ++mt2)
#pragma unroll
      for (int i = 0; i < 4; ++i) {
        const float a = __shfl(alpha[mt2], quad * 4 + i);
#pragma unroll
        for (int ntd = 0; ntd < 4; ++ntd) O[mt2][ntd][i] *= a;
      }

    // ---- O += P·V (P rows wave-private; compiler inserts lgkmcnt)
#pragma unroll
    for (int kf = 0; kf < 2; ++kf) {
      short8 bV[4];
#pragma unroll
      for (int ntd = 0; ntd < 4; ++ntd)
        bV[ntd] = *(const short8*)(Vt + ((kf * 4 + quad) * 64 + ntd * 16 + l15) * 8);
#pragma unroll
      for (int mt2 = 0; mt2 < 2; ++mt2) {
        short8 aP = *(const short8*)(
            QP + ((kf * 4 + quad) * 128 + w * 32 + mt2 * 16 + l15) * 8);
#pragma unroll
        for (int ntd = 0; ntd < 4; ++ntd)
          O[mt2][ntd] = __builtin_amdgcn_mfma_f32_16x16x32_bf16(
              aP, bV[ntd], O[mt2][ntd], 0, 0, 0);
      }
    }
  }

  // ---- epilogue: /l, bf16, overwrite own Q slots
#pragma unroll
  for (int mt2 = 0; mt2 < 2; ++mt2)
#pragma unroll
    for (int i = 0; i < 4; ++i) {
      const float linv = 1.0f / __shfl(l_i[mt2], quad * 4 + i);
      unsigned short* dst =
          qbase + (size_t)(q0 + w * 32 + mt2 * 16 + quad * 4 + i) * k3D;
#pragma unroll
      for (int ntd = 0; ntd < 4; ++ntd)
        dst[ntd * 16 + l15] = f2bf(O[mt2][ntd][i] * linv);
    }
}

// ---------------------------------------------------------------------------
extern "C" void kernel_launch(void* const* d_in, const int* in_sizes, int n_in,
                              void* d_out, int out_size, void* d_ws,
                              size_t ws_size, hipStream_t stream) {
  const float* x     = (const float*)d_in[0];
  const float* w_in  = (const float*)d_in[1];
  const float* b_in  = (const float*)d_in[2];
  const float* w_out = (const float*)d_in[3];
  const float* b_out = (const float*)d_in[4];
  const int*   cfl   = (const int*)d_in[5];
  float* out = (float*)d_out;

  // workspace layout (all 16B-aligned), total 92.3 MB
  char* ws = (char*)d_ws;
  unsigned short* qkvb = (unsigned short*)(ws);              // 8192x3072 bf16 = 48 MB
  unsigned short* xb   = (unsigned short*)(ws + 50331648);   // 8192x1024 bf16 = 16 MB
  unsigned short* wib  = (unsigned short*)(ws + 67108864);   // 3072x1024 bf16 =  6 MB
  unsigned short* wob  = (unsigned short*)(ws + 73400320);   // 1024x1024 bf16 =  2 MB
  unsigned short* vtb  = (unsigned short*)(ws + 75497472);   // [b,h,d,s] bf16 = 16 MB

  cvt_bf16<<<kM * kD / 4 / 256, 256, 0, stream>>>(x, xb, kM * kD / 4);
  cvt_bf16<<<k3D * kD / 4 / 256, 256, 0, stream>>>(w_in, wib, k3D * kD / 4);
  cvt_bf16<<<kD * kD / 4 / 256, 256, 0, stream>>>(w_out, wob, kD * kD / 4);

  // 1) qkv = x @ w_in^T + b_in (bf16 out; Q cols pre-scaled by 1/8)
  gemm_mfma<true, true><<<dim3(k3D / 128, kM / 128), 256, 0, stream>>>(
      xb, kD, wib, kD, b_in, qkvb, k3D, kD);

  // 2) V transpose for PV staging
  v_transpose<<<dim3(kS / 64, kH, kB), 256, 0, stream>>>(qkvb, vtb);

  // 3) flash attention (bf16 MFMA, S^T layout, register-Q), O overwrites Q slots
  flash_attn_mfma<<<dim3(kS / 128, kH, kB), 256, 0, stream>>>(qkvb, vtb, cfl);

  // 4) out = attn @ w_out^T + b_out (fp32 out; A rows inside qkvb, lda=3072)
  gemm_mfma<false, false><<<dim3(kD / 128, kM / 128), 256, 0, stream>>>(
      qkvb, k3D, wob, kD, b_out, out, kD, kD);
}

// Round 8
// 369.519 us; speedup vs baseline: 31.7936x; 1.0416x over previous
//
#include <hip/hip_runtime.h>
#include <hip/hip_bf16.h>
#include <stdint.h>

// Problem constants (B,S,D,H fixed by the reference)
constexpr int kB  = 4;
constexpr int kS  = 2048;
constexpr int kD  = 1024;
constexpr int kH  = 16;
constexpr int kDH = 64;
constexpr int kM  = kB * kS;     // 8192
constexpr int k3D = 3 * kD;      // 3072

// 0.125 (1/sqrt(DH)) * log2(e): scores leave GEMM1 in log2 domain -> exp2
constexpr float kQscale = 0.18033688011112042f;

typedef __attribute__((ext_vector_type(8))) short short8;  // 8 bf16 (4 VGPRs)
typedef __attribute__((ext_vector_type(4))) float f32x4;   // MFMA C/D

__device__ __forceinline__ float exp2v(float x) {
  return __builtin_amdgcn_exp2f(x);   // v_exp_f32 (base-2)
}

__device__ __forceinline__ unsigned short f2bf(float f) {
  unsigned u = __float_as_uint(f);
  u += 0x7fffu + ((u >> 16) & 1u);   // RNE
  return (unsigned short)(u >> 16);
}
__device__ __forceinline__ unsigned pack2bf(float a, float b) {
  return (unsigned)f2bf(a) | ((unsigned)f2bf(b) << 16);
}

// async global->LDS, 16B per lane. LDS dest must be wave-uniform base + lane*16.
__device__ __forceinline__ void async16(const void* g, void* l) {
  __builtin_amdgcn_global_load_lds(
      (const __attribute__((address_space(1))) unsigned int*)g,
      (__attribute__((address_space(3))) unsigned int*)l, 16, 0, 0);
}

// ---------------------------------------------------------------------------
// fp32 -> bf16 convert for all three inputs in one launch (saves 2 dispatches)
// ---------------------------------------------------------------------------
__global__ __launch_bounds__(256) void cvt_bf16_3(
    const float* __restrict__ x, const float* __restrict__ wi,
    const float* __restrict__ wo, unsigned short* __restrict__ xb,
    unsigned short* __restrict__ wib, unsigned short* __restrict__ wob) {
  constexpr int n_x  = kM * kD / 4;
  constexpr int n_wi = k3D * kD / 4;
  int i = blockIdx.x * 256 + threadIdx.x;
  const float* src;
  unsigned short* dst;
  int j;
  if (i < n_x)            { src = x;  dst = xb;  j = i; }
  else if (i < n_x + n_wi){ src = wi; dst = wib; j = i - n_x; }
  else                    { src = wo; dst = wob; j = i - n_x - n_wi; }
  float4 v = ((const float4*)src)[j];
  ushort4 r;
  r.x = f2bf(v.x); r.y = f2bf(v.y); r.z = f2bf(v.z); r.w = f2bf(v.w);
  ((ushort4*)dst)[j] = r;
}

// ---------------------------------------------------------------------------
// MFMA GEMM: C[M][N] = A[M][K](bf16) @ Bt[N][K](bf16)^T + bias (fp32 acc).
// 128x128 tile, BK=32, 4 waves 2x2. DOUBLE-BUFFERED LDS, ONE barrier per
// K-iter: tile it+1's global_load_lds is issued right after the barrier and
// stays in flight across the whole compute phase, so the compiler's
// vmcnt(0)-before-barrier waits on loads issued a full iteration earlier.
// QSCALE: multiply (acc+bias) by kQscale for output cols < kD (Q columns).
// ---------------------------------------------------------------------------
template <bool OUT_BF16, bool QSCALE>
__global__ __launch_bounds__(256) void gemm_mfma(
    const unsigned short* __restrict__ A, int lda,
    const unsigned short* __restrict__ Bt, int ldb,
    const float* __restrict__ bias, void* __restrict__ Cp, int ldc, int K) {
  __shared__ unsigned short As[2][4096];  // 16 KB
  __shared__ unsigned short Bs[2][4096];  // 16 KB
  const int t = threadIdx.x;
  const int lane = t & 63, l15 = lane & 15, quad = lane >> 4, w = t >> 6;
  const int row0 = blockIdx.y * 128, col0 = blockIdx.x * 128;
  const int wm = (w & 1) * 64, wn = (w >> 1) * 64;

  f32x4 acc[4][4] = {};

  const int q1 = t, q2 = t + 256;  // chunk ids; q = t keeps wave-contiguity
  const unsigned short* a1 = A  + (size_t)(row0 + (q1 & 127)) * lda + (q1 >> 7) * 8;
  const unsigned short* a2 = A  + (size_t)(row0 + (q2 & 127)) * lda + (q2 >> 7) * 8;
  const unsigned short* b1 = Bt + (size_t)(col0 + (q1 & 127)) * ldb + (q1 >> 7) * 8;
  const unsigned short* b2 = Bt + (size_t)(col0 + (q2 & 127)) * ldb + (q2 >> 7) * 8;

  const int nIter = K / 32;
  // prologue: stage tile 0 into buf 0
  async16(a1, As[0] + q1 * 8);
  async16(a2, As[0] + q2 * 8);
  async16(b1, Bs[0] + q1 * 8);
  async16(b2, Bs[0] + q2 * 8);

  for (int it = 0; it < nIter; ++it) {
    __syncthreads();  // drains tile 'it' staging (issued a full iter ago)
    const int cb = it & 1, nb = cb ^ 1;
    if (it + 1 < nIter) {
      const int k0 = (it + 1) * 32;
      async16(a1 + k0, As[nb] + q1 * 8);
      async16(a2 + k0, As[nb] + q2 * 8);
      async16(b1 + k0, Bs[nb] + q1 * 8);
      async16(b2 + k0, Bs[nb] + q2 * 8);
    }
    short8 af[4], bf[4];
#pragma unroll
    for (int mt = 0; mt < 4; ++mt)
      af[mt] = *(const short8*)(As[cb] + (quad * 128 + wm + mt * 16 + l15) * 8);
#pragma unroll
    for (int nt = 0; nt < 4; ++nt)
      bf[nt] = *(const short8*)(Bs[cb] + (quad * 128 + wn + nt * 16 + l15) * 8);
#pragma unroll
    for (int mt = 0; mt < 4; ++mt)
#pragma unroll
      for (int nt = 0; nt < 4; ++nt)
        acc[mt][nt] = __builtin_amdgcn_mfma_f32_16x16x32_bf16(
            af[mt], bf[nt], acc[mt][nt], 0, 0, 0);
  }

  const float sc = (QSCALE && col0 < kD) ? kQscale : 1.0f;
  float bv[4];
#pragma unroll
  for (int nt = 0; nt < 4; ++nt) bv[nt] = bias[col0 + wn + nt * 16 + l15];
#pragma unroll
  for (int mt = 0; mt < 4; ++mt)
#pragma unroll
    for (int i = 0; i < 4; ++i) {
      const size_t r = (size_t)(row0 + wm + mt * 16 + quad * 4 + i);
#pragma unroll
      for (int nt = 0; nt < 4; ++nt) {
        float v = (acc[mt][nt][i] + bv[nt]) * sc;
        const size_t cidx = r * (size_t)ldc + col0 + wn + nt * 16 + l15;
        if (OUT_BF16) ((unsigned short*)Cp)[cidx] = f2bf(v);
        else          ((float*)Cp)[cidx] = v;
      }
    }
}

// ---------------------------------------------------------------------------
// V transpose: qkvb V-slots [b*S+s][2048 + h*64 + d] -> vtb [(b*16+h)*64+d][s]
// ---------------------------------------------------------------------------
__global__ __launch_bounds__(256) void v_transpose(
    const unsigned short* __restrict__ qkvb, unsigned short* __restrict__ vtb) {
  __shared__ unsigned short L[64][72];  // +8 pad: 16B-aligned rows
  const int kt = blockIdx.x, h = blockIdx.y, b = blockIdx.z;
  const int t = threadIdx.x;
  const unsigned short* src = qkvb + (size_t)(b * kS) * k3D + 2 * kD + h * kDH;
#pragma unroll
  for (int p = 0; p < 2; ++p) {
    const int q = t + p * 256;
    const int r = q >> 3, c = q & 7;
    *(short8*)(&L[r][c * 8]) =
        *(const short8*)(src + (size_t)(kt * 64 + r) * k3D + c * 8);
  }
  __syncthreads();
  unsigned short* dst = vtb + (size_t)((b * kH + h) * kDH) * kS + kt * 64;
  const int key2 = (t & 31) * 2, dg = t >> 5;
#pragma unroll
  for (int i = 0; i < 8; ++i) {
    const int d = dg * 8 + i;
    ushort2 v = make_ushort2(L[key2][d], L[key2 + 1][d]);
    *(ushort2*)(dst + (size_t)d * kS + key2) = v;  // coalesced along keys
  }
}

// ---------------------------------------------------------------------------
// MFMA flash attention, S^T formulation, register-Q, software-pipelined
// staging: K(kt+1) issued after the mid barrier (in flight across softmax+PV),
// V(kt+1) issued after the end barrier (in flight across next QK^T+softmax).
// Both vmcnt(0)-before-barrier drains now wait on loads issued a full compute
// phase earlier. Single K/V buffers, 32 KB LDS total, 4 blocks/CU.
// ---------------------------------------------------------------------------
__global__ __launch_bounds__(256, 4) void flash_attn_mfma(
    unsigned short* __restrict__ qkvb, const unsigned short* __restrict__ vtb,
    const int* __restrict__ cflag) {
  __shared__ unsigned short QP[8192];  // Q then P: [chunk 0..7][q 0..127][8] 16 KB
  __shared__ unsigned short Ks[4096];  // [dchunk 0..7][key 0..63][8]          8 KB
  __shared__ unsigned short Vt[4096];  // [keychunk 0..7][d 0..63][8]          8 KB

  const int qt = (int)gridDim.x - 1 - (int)blockIdx.x;
  const int h = blockIdx.y, b = blockIdx.z;
  const int t = threadIdx.x;
  const int lane = t & 63, l15 = lane & 15, quad = lane >> 4, w = t >> 6;
  const int q0 = qt * 128;
  const bool causal = (*cflag) != 0;
  const int ntiles = causal ? (2 * qt + 2) : (kS / 64);

  unsigned short* qbase = qkvb + (size_t)(b * kS) * k3D + h * kDH;
  const unsigned short* vbase = vtb + (size_t)((b * kH + h) * kDH) * kS;

  const int c0 = t, c1 = t + 256;

  // ---- prologue: stage Q (4 chunks/thread) + K tile 0
#pragma unroll
  for (int p = 0; p < 4; ++p) {
    const int c = t + p * 256;
    async16(qbase + (size_t)(q0 + (c & 127)) * k3D + (c >> 7) * 8, QP + c * 8);
  }
  async16(qbase + kD + (size_t)(c0 & 63) * k3D + (c0 >> 6) * 8, Ks + c0 * 8);
  async16(qbase + kD + (size_t)(c1 & 63) * k3D + (c1 >> 6) * 8, Ks + c1 * 8);
  __syncthreads();  // drains Q + K0

  // hoist Q fragments to registers — QP becomes the P buffer afterwards.
  // (Safe: first P write is after B_mid(0); every wave's bq reads precede it.)
  short8 bq[2][2];
#pragma unroll
  for (int nt = 0; nt < 2; ++nt)
#pragma unroll
    for (int kf = 0; kf < 2; ++kf)
      bq[nt][kf] = *(const short8*)(
          QP + ((kf * 4 + quad) * 128 + w * 32 + nt * 16 + l15) * 8);

  // V tile 0 (in flight across QK^T(0); drained at B_mid(0))
  async16(vbase + (size_t)(c0 & 63) * kS + (c0 >> 6) * 8, Vt + c0 * 8);
  async16(vbase + (size_t)(c1 & 63) * kS + (c1 >> 6) * 8, Vt + c1 * 8);

  f32x4 O[2][4] = {};                      // [q-half mt2][d-tile ntd]
  float m_i[2] = {-3.0e38f, -3.0e38f};     // per q-group (q = w*32+nt*16+l15)
  float l_i[2] = {0.f, 0.f};

  for (int kt = 0; kt < ntiles; ++kt) {
    const int kk0 = kt * 64;

    // ---- S^T = K·Q^T (Ks staged: B0 for kt=0, B_end(kt-1) for kt>0)
    f32x4 s[4][2];
#pragma unroll
    for (int mt = 0; mt < 4; ++mt) {
      short8 a0 = *(const short8*)(Ks + ((quad)*64 + mt * 16 + l15) * 8);
      short8 a1 = *(const short8*)(Ks + ((4 + quad) * 64 + mt * 16 + l15) * 8);
#pragma unroll
      for (int nt = 0; nt < 2; ++nt) {
        f32x4 z = {};
        z = __builtin_amdgcn_mfma_f32_16x16x32_bf16(a0, bq[nt][0], z, 0, 0, 0);
        z = __builtin_amdgcn_mfma_f32_16x16x32_bf16(a1, bq[nt][1], z, 0, 0, 0);
        s[mt][nt] = z;
      }
    }

    __syncthreads();  // B_mid: drains V(kt); all QK^T reads of Ks complete

    // issue K(kt+1) — in flight across softmax + PV, drained at B_end
    if (kt + 1 < ntiles) {
      const int kn = kk0 + 64;
      async16(qbase + kD + (size_t)(kn + (c0 & 63)) * k3D + (c0 >> 6) * 8,
              Ks + c0 * 8);
      async16(qbase + kD + (size_t)(kn + (c1 & 63)) * k3D + (c1 >> 6) * 8,
              Ks + c1 * 8);
    }

    // ---- online softmax per q-group nt (scores are in log2 domain)
    float alpha[2];
#pragma unroll
    for (int nt = 0; nt < 2; ++nt) {
      const int gq = q0 + w * 32 + nt * 16 + l15;
      if (causal && kt >= ntiles - 2) {
#pragma unroll
        for (int mt = 0; mt < 4; ++mt)
#pragma unroll
          for (int i = 0; i < 4; ++i)
            if (kk0 + mt * 16 + quad * 4 + i > gq) s[mt][nt][i] = -3.0e38f;
      }
      float mx = -3.0e38f;
#pragma unroll
      for (int mt = 0; mt < 4; ++mt)
#pragma unroll
        for (int i = 0; i < 4; ++i) mx = fmaxf(mx, s[mt][nt][i]);
      mx = fmaxf(mx, __shfl_xor(mx, 16));
      mx = fmaxf(mx, __shfl_xor(mx, 32));
      const float mn = fmaxf(m_i[nt], mx);
      alpha[nt] = exp2v(m_i[nt] - mn);
      m_i[nt] = mn;

      float p[4][4];
      float rs = 0.f;
#pragma unroll
      for (int mt = 0; mt < 4; ++mt)
#pragma unroll
        for (int i = 0; i < 4; ++i) {
          p[mt][i] = exp2v(s[mt][nt][i] - mn);
          rs += p[mt][i];
        }
      rs += __shfl_xor(rs, 16);
      rs += __shfl_xor(rs, 32);
      l_i[nt] = l_i[nt] * alpha[nt] + rs;

      // packed P store: 4 consecutive keys (mt*16+quad*4 .. +3) at row gq
#pragma unroll
      for (int mt = 0; mt < 4; ++mt) {
        uint2 pk = make_uint2(pack2bf(p[mt][0], p[mt][1]),
                              pack2bf(p[mt][2], p[mt][3]));
        *(uint2*)(QP + ((mt * 2 + (quad >> 1)) * 128 + w * 32 + nt * 16 + l15) * 8 +
                  (quad & 1) * 4) = pk;
      }
    }

    // ---- rescale O by alpha of its own q-row (row = mt2*16 + quad*4 + i)
#pragma unroll
    for (int mt2 = 0; mt2 < 2; ++mt2)
#pragma unroll
      for (int i = 0; i < 4; ++i) {
        const float a = __shfl(alpha[mt2], quad * 4 + i);
#pragma unroll
        for (int ntd = 0; ntd < 4; ++ntd) O[mt2][ntd][i] *= a;
      }

    // ---- O += P·V (P rows wave-private; Vt drained at B_mid)
#pragma unroll
    for (int kf = 0; kf < 2; ++kf) {
      short8 bV[4];
#pragma unroll
      for (int ntd = 0; ntd < 4; ++ntd)
        bV[ntd] = *(const short8*)(Vt + ((kf * 4 + quad) * 64 + ntd * 16 + l15) * 8);
#pragma unroll
      for (int mt2 = 0; mt2 < 2; ++mt2) {
        short8 aP = *(const short8*)(
            QP + ((kf * 4 + quad) * 128 + w * 32 + mt2 * 16 + l15) * 8);
#pragma unroll
        for (int ntd = 0; ntd < 4; ++ntd)
          O[mt2][ntd] = __builtin_amdgcn_mfma_f32_16x16x32_bf16(
              aP, bV[ntd], O[mt2][ntd], 0, 0, 0);
      }
    }

    __syncthreads();  // B_end: drains K(kt+1); all PV reads of Vt complete

    // issue V(kt+1) — in flight across next QK^T + softmax, drained at B_mid
    if (kt + 1 < ntiles) {
      const int kn = kk0 + 64;
      async16(vbase + (size_t)(c0 & 63) * kS + kn + (c0 >> 6) * 8, Vt + c0 * 8);
      async16(vbase + (size_t)(c1 & 63) * kS + kn + (c1 >> 6) * 8, Vt + c1 * 8);
    }
  }

  // ---- epilogue: /l, bf16, overwrite own Q slots
#pragma unroll
  for (int mt2 = 0; mt2 < 2; ++mt2)
#pragma unroll
    for (int i = 0; i < 4; ++i) {
      const float linv = 1.0f / __shfl(l_i[mt2], quad * 4 + i);
      unsigned short* dst =
          qbase + (size_t)(q0 + w * 32 + mt2 * 16 + quad * 4 + i) * k3D;
#pragma unroll
      for (int ntd = 0; ntd < 4; ++ntd)
        dst[ntd * 16 + l15] = f2bf(O[mt2][ntd][i] * linv);
    }
}

// ---------------------------------------------------------------------------
extern "C" void kernel_launch(void* const* d_in, const int* in_sizes, int n_in,
                              void* d_out, int out_size, void* d_ws,
                              size_t ws_size, hipStream_t stream) {
  const float* x     = (const float*)d_in[0];
  const float* w_in  = (const float*)d_in[1];
  const float* b_in  = (const float*)d_in[2];
  const float* w_out = (const float*)d_in[3];
  const float* b_out = (const float*)d_in[4];
  const int*   cfl   = (const int*)d_in[5];
  float* out = (float*)d_out;

  // workspace layout (all 16B-aligned), total 92.3 MB
  char* ws = (char*)d_ws;
  unsigned short* qkvb = (unsigned short*)(ws);              // 8192x3072 bf16 = 48 MB
  unsigned short* xb   = (unsigned short*)(ws + 50331648);   // 8192x1024 bf16 = 16 MB
  unsigned short* wib  = (unsigned short*)(ws + 67108864);   // 3072x1024 bf16 =  6 MB
  unsigned short* wob  = (unsigned short*)(ws + 73400320);   // 1024x1024 bf16 =  2 MB
  unsigned short* vtb  = (unsigned short*)(ws + 75497472);   // [b,h,d,s] bf16 = 16 MB

  // 0) all three fp32->bf16 conversions in one launch
  cvt_bf16_3<<<(kM * kD + k3D * kD + kD * kD) / 4 / 256, 256, 0, stream>>>(
      x, w_in, w_out, xb, wib, wob);

  // 1) qkv = x @ w_in^T + b_in (bf16 out; Q cols pre-scaled by 0.125*log2e)
  gemm_mfma<true, true><<<dim3(k3D / 128, kM / 128), 256, 0, stream>>>(
      xb, kD, wib, kD, b_in, qkvb, k3D, kD);

  // 2) V transpose for PV staging
  v_transpose<<<dim3(kS / 64, kH, kB), 256, 0, stream>>>(qkvb, vtb);

  // 3) flash attention (bf16 MFMA, S^T layout, register-Q, pipelined staging)
  flash_attn_mfma<<<dim3(kS / 128, kH, kB), 256, 0, stream>>>(qkvb, vtb, cfl);

  // 4) out = attn @ w_out^T + b_out (fp32 out; A rows inside qkvb, lda=3072)
  gemm_mfma<false, false><<<dim3(kD / 128, kM / 128), 256, 0, stream>>>(
      qkvb, k3D, wob, kD, b_out, out, kD, kD);
}

// Round 9
// 357.454 us; speedup vs baseline: 32.8668x; 1.0338x over previous
//
#include <hip/hip_runtime.h>
#include <hip/hip_bf16.h>
#include <stdint.h>

// Problem constants (B,S,D,H fixed by the reference)
constexpr int kB  = 4;
constexpr int kS  = 2048;
constexpr int kD  = 1024;
constexpr int kH  = 16;
constexpr int kDH = 64;
constexpr int kM  = kB * kS;     // 8192
constexpr int k3D = 3 * kD;      // 3072

// 0.125 (1/sqrt(DH)) * log2(e): scores leave GEMM1 in log2 domain -> exp2
constexpr float kQscale = 0.18033688011112042f;

typedef __attribute__((ext_vector_type(8))) short short8;  // 8 bf16 (4 VGPRs)
typedef __attribute__((ext_vector_type(4))) float f32x4;   // MFMA C/D

__device__ __forceinline__ float exp2v(float x) {
  return __builtin_amdgcn_exp2f(x);   // v_exp_f32 (base-2)
}

__device__ __forceinline__ unsigned short f2bf(float f) {
  unsigned u = __float_as_uint(f);
  u += 0x7fffu + ((u >> 16) & 1u);   // RNE
  return (unsigned short)(u >> 16);
}
__device__ __forceinline__ unsigned pack2bf(float a, float b) {
  return (unsigned)f2bf(a) | ((unsigned)f2bf(b) << 16);
}

// async global->LDS, 16B per lane. LDS dest must be wave-uniform base + lane*16.
__device__ __forceinline__ void async16(const void* g, void* l) {
  __builtin_amdgcn_global_load_lds(
      (const __attribute__((address_space(1))) unsigned int*)g,
      (__attribute__((address_space(3))) unsigned int*)l, 16, 0, 0);
}

// ---------------------------------------------------------------------------
// fp32 -> bf16 convert for all three inputs in one launch
// ---------------------------------------------------------------------------
__global__ __launch_bounds__(256) void cvt_bf16_3(
    const float* __restrict__ x, const float* __restrict__ wi,
    const float* __restrict__ wo, unsigned short* __restrict__ xb,
    unsigned short* __restrict__ wib, unsigned short* __restrict__ wob) {
  constexpr int n_x  = kM * kD / 4;
  constexpr int n_wi = k3D * kD / 4;
  int i = blockIdx.x * 256 + threadIdx.x;
  const float* src;
  unsigned short* dst;
  int j;
  if (i < n_x)            { src = x;  dst = xb;  j = i; }
  else if (i < n_x + n_wi){ src = wi; dst = wib; j = i - n_x; }
  else                    { src = wo; dst = wob; j = i - n_x - n_wi; }
  float4 v = ((const float4*)src)[j];
  ushort4 r;
  r.x = f2bf(v.x); r.y = f2bf(v.y); r.z = f2bf(v.z); r.w = f2bf(v.w);
  ((ushort4*)dst)[j] = r;
}

// ---------------------------------------------------------------------------
// MFMA GEMM: C[M][N] = A[M][K](bf16) @ Bt[N][K](bf16)^T + bias (fp32 acc).
// 128x128 tile, BK=32, 4 waves 2x2, double-buffered LDS, one barrier/K-iter.
// QSCALE: multiply (acc+bias) by kQscale for output cols < kD (Q columns).
// ---------------------------------------------------------------------------
template <bool OUT_BF16, bool QSCALE>
__global__ __launch_bounds__(256) void gemm_mfma(
    const unsigned short* __restrict__ A, int lda,
    const unsigned short* __restrict__ Bt, int ldb,
    const float* __restrict__ bias, void* __restrict__ Cp, int ldc, int K) {
  __shared__ unsigned short As[2][4096];  // 16 KB
  __shared__ unsigned short Bs[2][4096];  // 16 KB
  const int t = threadIdx.x;
  const int lane = t & 63, l15 = lane & 15, quad = lane >> 4, w = t >> 6;
  const int row0 = blockIdx.y * 128, col0 = blockIdx.x * 128;
  const int wm = (w & 1) * 64, wn = (w >> 1) * 64;

  f32x4 acc[4][4] = {};

  const int q1 = t, q2 = t + 256;  // chunk ids; q = t keeps wave-contiguity
  const unsigned short* a1 = A  + (size_t)(row0 + (q1 & 127)) * lda + (q1 >> 7) * 8;
  const unsigned short* a2 = A  + (size_t)(row0 + (q2 & 127)) * lda + (q2 >> 7) * 8;
  const unsigned short* b1 = Bt + (size_t)(col0 + (q1 & 127)) * ldb + (q1 >> 7) * 8;
  const unsigned short* b2 = Bt + (size_t)(col0 + (q2 & 127)) * ldb + (q2 >> 7) * 8;

  const int nIter = K / 32;
  async16(a1, As[0] + q1 * 8);
  async16(a2, As[0] + q2 * 8);
  async16(b1, Bs[0] + q1 * 8);
  async16(b2, Bs[0] + q2 * 8);

  for (int it = 0; it < nIter; ++it) {
    __syncthreads();  // drains tile 'it' staging (issued a full iter ago)
    const int cb = it & 1, nb = cb ^ 1;
    if (it + 1 < nIter) {
      const int k0 = (it + 1) * 32;
      async16(a1 + k0, As[nb] + q1 * 8);
      async16(a2 + k0, As[nb] + q2 * 8);
      async16(b1 + k0, Bs[nb] + q1 * 8);
      async16(b2 + k0, Bs[nb] + q2 * 8);
    }
    short8 af[4], bf[4];
#pragma unroll
    for (int mt = 0; mt < 4; ++mt)
      af[mt] = *(const short8*)(As[cb] + (quad * 128 + wm + mt * 16 + l15) * 8);
#pragma unroll
    for (int nt = 0; nt < 4; ++nt)
      bf[nt] = *(const short8*)(Bs[cb] + (quad * 128 + wn + nt * 16 + l15) * 8);
#pragma unroll
    for (int mt = 0; mt < 4; ++mt)
#pragma unroll
      for (int nt = 0; nt < 4; ++nt)
        acc[mt][nt] = __builtin_amdgcn_mfma_f32_16x16x32_bf16(
            af[mt], bf[nt], acc[mt][nt], 0, 0, 0);
  }

  const float sc = (QSCALE && col0 < kD) ? kQscale : 1.0f;
  float bv[4];
#pragma unroll
  for (int nt = 0; nt < 4; ++nt) bv[nt] = bias[col0 + wn + nt * 16 + l15];
#pragma unroll
  for (int mt = 0; mt < 4; ++mt)
#pragma unroll
    for (int i = 0; i < 4; ++i) {
      const size_t r = (size_t)(row0 + wm + mt * 16 + quad * 4 + i);
#pragma unroll
      for (int nt = 0; nt < 4; ++nt) {
        float v = (acc[mt][nt][i] + bv[nt]) * sc;
        const size_t cidx = r * (size_t)ldc + col0 + wn + nt * 16 + l15;
        if (OUT_BF16) ((unsigned short*)Cp)[cidx] = f2bf(v);
        else          ((float*)Cp)[cidx] = v;
      }
    }
}

// ---------------------------------------------------------------------------
// V transpose: qkvb V-slots [b*S+s][2048 + h*64 + d] -> vtb [(b*16+h)*64+d][s]
// ---------------------------------------------------------------------------
__global__ __launch_bounds__(256) void v_transpose(
    const unsigned short* __restrict__ qkvb, unsigned short* __restrict__ vtb) {
  __shared__ unsigned short L[64][72];  // +8 pad: 16B-aligned rows
  const int kt = blockIdx.x, h = blockIdx.y, b = blockIdx.z;
  const int t = threadIdx.x;
  const unsigned short* src = qkvb + (size_t)(b * kS) * k3D + 2 * kD + h * kDH;
#pragma unroll
  for (int p = 0; p < 2; ++p) {
    const int q = t + p * 256;
    const int r = q >> 3, c = q & 7;
    *(short8*)(&L[r][c * 8]) =
        *(const short8*)(src + (size_t)(kt * 64 + r) * k3D + c * 8);
  }
  __syncthreads();
  unsigned short* dst = vtb + (size_t)((b * kH + h) * kDH) * kS + kt * 64;
  const int key2 = (t & 31) * 2, dg = t >> 5;
#pragma unroll
  for (int i = 0; i < 8; ++i) {
    const int d = dg * 8 + i;
    ushort2 v = make_ushort2(L[key2][d], L[key2 + 1][d]);
    *(ushort2*)(dst + (size_t)d * kS + key2) = v;  // coalesced along keys
  }
}

// ---------------------------------------------------------------------------
// MFMA flash attention, S^T formulation, register-Q, pipelined staging,
// COMPLEMENTARY-PAIR BALANCED: block = (b, h, pair p) handles q-tiles p and
// 31-p (64 rows each). Causal work = (p+1) + (32-p) = 33 k-tiles for EVERY
// block -> zero tail, 4 blocks/CU (16 waves) sustained for the whole kernel.
// 24 KB LDS. 4 waves x 16 q-rows per q-tile.
// ---------------------------------------------------------------------------
__global__ __launch_bounds__(256, 4) void flash_attn_mfma(
    unsigned short* __restrict__ qkvb, const unsigned short* __restrict__ vtb,
    const int* __restrict__ cflag) {
  __shared__ unsigned short QP[4096];  // Q then P: [chunk 0..7][q 0..63][8] 8 KB
  __shared__ unsigned short Ks[4096];  // [dchunk 0..7][key 0..63][8]        8 KB
  __shared__ unsigned short Vt[4096];  // [keychunk 0..7][d 0..63][8]        8 KB

  const int pr = blockIdx.x;           // pair id 0..15
  const int h = blockIdx.y, b = blockIdx.z;
  const int t = threadIdx.x;
  const int lane = t & 63, l15 = lane & 15, quad = lane >> 4, w = t >> 6;
  const bool causal = (*cflag) != 0;

  unsigned short* qbase = qkvb + (size_t)(b * kS) * k3D + h * kDH;
  const unsigned short* vbase = vtb + (size_t)((b * kH + h) * kDH) * kS;
  const int c0 = t, c1 = t + 256;

  for (int half = 0; half < 2; ++half) {
    const int qt = half ? (31 - pr) : pr;
    const int q0 = qt * 64;
    const int ntiles = causal ? (qt + 1) : 32;

    // ---- prologue: stage Q (512 chunks) + K tile 0
    // (safe vs previous half: its last B_end ordered all LDS reads before this)
    async16(qbase + (size_t)(q0 + (c0 & 63)) * k3D + (c0 >> 6) * 8, QP + c0 * 8);
    async16(qbase + (size_t)(q0 + (c1 & 63)) * k3D + (c1 >> 6) * 8, QP + c1 * 8);
    async16(qbase + kD + (size_t)(c0 & 63) * k3D + (c0 >> 6) * 8, Ks + c0 * 8);
    async16(qbase + kD + (size_t)(c1 & 63) * k3D + (c1 >> 6) * 8, Ks + c1 * 8);
    __syncthreads();  // drains Q + K0

    // hoist Q fragments to registers — QP becomes the P buffer afterwards
    short8 bq[2];
#pragma unroll
    for (int kf = 0; kf < 2; ++kf)
      bq[kf] = *(const short8*)(
          QP + ((kf * 4 + quad) * 64 + w * 16 + l15) * 8);

    // V tile 0 (in flight across QK^T(0); drained at B_mid(0))
    async16(vbase + (size_t)(c0 & 63) * kS + (c0 >> 6) * 8, Vt + c0 * 8);
    async16(vbase + (size_t)(c1 & 63) * kS + (c1 >> 6) * 8, Vt + c1 * 8);

    f32x4 O[4] = {};                  // [d-tile ntd]; q row = w*16+quad*4+i
    float m_i = -3.0e38f, l_i = 0.f;  // per q (q = w*16+l15)

    for (int kt = 0; kt < ntiles; ++kt) {
      const int kk0 = kt * 64;

      // ---- S^T = K·Q^T: key = kk0+mt*16+quad*4+reg, q = w*16+l15
      f32x4 s[4];
#pragma unroll
      for (int mt = 0; mt < 4; ++mt) {
        short8 a0 = *(const short8*)(Ks + ((quad)*64 + mt * 16 + l15) * 8);
        short8 a1 = *(const short8*)(Ks + ((4 + quad) * 64 + mt * 16 + l15) * 8);
        f32x4 z = {};
        z = __builtin_amdgcn_mfma_f32_16x16x32_bf16(a0, bq[0], z, 0, 0, 0);
        z = __builtin_amdgcn_mfma_f32_16x16x32_bf16(a1, bq[1], z, 0, 0, 0);
        s[mt] = z;
      }

      __syncthreads();  // B_mid: drains V(kt); all QK^T reads of Ks complete

      // issue K(kt+1) — in flight across softmax + PV, drained at B_end
      if (kt + 1 < ntiles) {
        const int kn = kk0 + 64;
        async16(qbase + kD + (size_t)(kn + (c0 & 63)) * k3D + (c0 >> 6) * 8,
                Ks + c0 * 8);
        async16(qbase + kD + (size_t)(kn + (c1 & 63)) * k3D + (c1 >> 6) * 8,
                Ks + c1 * 8);
      }

      // ---- online softmax (scores in log2 domain; diagonal tile masked)
      const int gq = q0 + w * 16 + l15;
      if (causal && kt == ntiles - 1) {
#pragma unroll
        for (int mt = 0; mt < 4; ++mt)
#pragma unroll
          for (int i = 0; i < 4; ++i)
            if (kk0 + mt * 16 + quad * 4 + i > gq) s[mt][i] = -3.0e38f;
      }
      float mx = -3.0e38f;
#pragma unroll
      for (int mt = 0; mt < 4; ++mt)
#pragma unroll
        for (int i = 0; i < 4; ++i) mx = fmaxf(mx, s[mt][i]);
      mx = fmaxf(mx, __shfl_xor(mx, 16));
      mx = fmaxf(mx, __shfl_xor(mx, 32));
      const float mn = fmaxf(m_i, mx);
      const float alpha = exp2v(m_i - mn);
      m_i = mn;

      float p[4][4];
      float rs = 0.f;
#pragma unroll
      for (int mt = 0; mt < 4; ++mt)
#pragma unroll
        for (int i = 0; i < 4; ++i) {
          p[mt][i] = exp2v(s[mt][i] - mn);
          rs += p[mt][i];
        }
      rs += __shfl_xor(rs, 16);
      rs += __shfl_xor(rs, 32);
      l_i = l_i * alpha + rs;

      // packed P store: 4 consecutive keys (mt*16+quad*4 .. +3) at row gq
#pragma unroll
      for (int mt = 0; mt < 4; ++mt) {
        uint2 pk = make_uint2(pack2bf(p[mt][0], p[mt][1]),
                              pack2bf(p[mt][2], p[mt][3]));
        *(uint2*)(QP + ((mt * 2 + (quad >> 1)) * 64 + w * 16 + l15) * 8 +
                  (quad & 1) * 4) = pk;
      }

      // ---- rescale O by alpha of its own q-row (row = w*16 + quad*4 + i)
#pragma unroll
      for (int i = 0; i < 4; ++i) {
        const float a = __shfl(alpha, quad * 4 + i);
#pragma unroll
        for (int ntd = 0; ntd < 4; ++ntd) O[ntd][i] *= a;
      }

      // ---- O += P·V (P rows wave-private; Vt drained at B_mid)
#pragma unroll
      for (int kf = 0; kf < 2; ++kf) {
        short8 aP = *(const short8*)(
            QP + ((kf * 4 + quad) * 64 + w * 16 + l15) * 8);
#pragma unroll
        for (int ntd = 0; ntd < 4; ++ntd) {
          short8 bV = *(const short8*)(
              Vt + ((kf * 4 + quad) * 64 + ntd * 16 + l15) * 8);
          O[ntd] = __builtin_amdgcn_mfma_f32_16x16x32_bf16(
              aP, bV, O[ntd], 0, 0, 0);
        }
      }

      __syncthreads();  // B_end: drains K(kt+1); all PV reads of Vt/QP complete

      // issue V(kt+1) — in flight across next QK^T + softmax
      if (kt + 1 < ntiles) {
        const int kn = kk0 + 64;
        async16(vbase + (size_t)(c0 & 63) * kS + kn + (c0 >> 6) * 8, Vt + c0 * 8);
        async16(vbase + (size_t)(c1 & 63) * kS + kn + (c1 >> 6) * 8, Vt + c1 * 8);
      }
    }

    // ---- epilogue: /l, bf16, overwrite own Q slots
#pragma unroll
    for (int i = 0; i < 4; ++i) {
      const float linv = 1.0f / __shfl(l_i, quad * 4 + i);
      unsigned short* dst =
          qbase + (size_t)(q0 + w * 16 + quad * 4 + i) * k3D;
#pragma unroll
      for (int ntd = 0; ntd < 4; ++ntd)
        dst[ntd * 16 + l15] = f2bf(O[ntd][i] * linv);
    }
  }
}

// ---------------------------------------------------------------------------
extern "C" void kernel_launch(void* const* d_in, const int* in_sizes, int n_in,
                              void* d_out, int out_size, void* d_ws,
                              size_t ws_size, hipStream_t stream) {
  const float* x     = (const float*)d_in[0];
  const float* w_in  = (const float*)d_in[1];
  const float* b_in  = (const float*)d_in[2];
  const float* w_out = (const float*)d_in[3];
  const float* b_out = (const float*)d_in[4];
  const int*   cfl   = (const int*)d_in[5];
  float* out = (float*)d_out;

  // workspace layout (all 16B-aligned), total 92.3 MB
  char* ws = (char*)d_ws;
  unsigned short* qkvb = (unsigned short*)(ws);              // 8192x3072 bf16 = 48 MB
  unsigned short* xb   = (unsigned short*)(ws + 50331648);   // 8192x1024 bf16 = 16 MB
  unsigned short* wib  = (unsigned short*)(ws + 67108864);   // 3072x1024 bf16 =  6 MB
  unsigned short* wob  = (unsigned short*)(ws + 73400320);   // 1024x1024 bf16 =  2 MB
  unsigned short* vtb  = (unsigned short*)(ws + 75497472);   // [b,h,d,s] bf16 = 16 MB

  // 0) all three fp32->bf16 conversions in one launch
  cvt_bf16_3<<<(kM * kD + k3D * kD + kD * kD) / 4 / 256, 256, 0, stream>>>(
      x, w_in, w_out, xb, wib, wob);

  // 1) qkv = x @ w_in^T + b_in (bf16 out; Q cols pre-scaled by 0.125*log2e)
  gemm_mfma<true, true><<<dim3(k3D / 128, kM / 128), 256, 0, stream>>>(
      xb, kD, wib, kD, b_in, qkvb, k3D, kD);

  // 2) V transpose for PV staging
  v_transpose<<<dim3(kS / 64, kH, kB), 256, 0, stream>>>(qkvb, vtb);

  // 3) flash attention (pair-balanced, bf16 MFMA, register-Q, pipelined)
  flash_attn_mfma<<<dim3(16, kH, kB), 256, 0, stream>>>(qkvb, vtb, cfl);

  // 4) out = attn @ w_out^T + b_out (fp32 out; A rows inside qkvb, lda=3072)
  gemm_mfma<false, false><<<dim3(kD / 128, kM / 128), 256, 0, stream>>>(
      qkvb, k3D, wob, kD, b_out, out, kD, kD);
}